// Round 8
// baseline (142.105 us; speedup 1.0000x reference)
//
#include <hip/hip_runtime.h>
#include <hip/hip_bf16.h>
#include <stdint.h>

#define NPIX 512
#define NBC  96
#define NWG8 (NBC * 4)      // 384 blocks: 96 images x 2x2 tiles of 256^2

typedef __attribute__((ext_vector_type(8))) short bf16x8;
typedef __attribute__((ext_vector_type(4))) float f32x4;
typedef __attribute__((ext_vector_type(8))) unsigned short u16x8;

__device__ __forceinline__ unsigned short f2bf(float f) {
    __hip_bfloat16 h = __float2bfloat16(f);
    union { __hip_bfloat16 h; unsigned short u; } v;
    v.h = h;
    return v.u;
}

#define GLD16(g, l) __builtin_amdgcn_global_load_lds( \
    (const __attribute__((address_space(1))) void*)(const void*)(g), \
    (__attribute__((address_space(3))) void*)(void*)(l), 16, 0, 0)

#define SBAR() do { __builtin_amdgcn_sched_barrier(0); \
                    __builtin_amdgcn_s_barrier(); \
                    __builtin_amdgcn_sched_barrier(0); } while (0)
#define LGKM0() do { asm volatile("s_waitcnt lgkmcnt(0)" ::: "memory"); \
                     __builtin_amdgcn_sched_barrier(0); } while (0)
#define SB0() __builtin_amdgcn_sched_barrier(0)

// ---------------- D basis: D[k][n] = bf16(2*cos(pi*(2n+1)*k/1024)) ----------------
__global__ void k_basis(unsigned short* __restrict__ D) {
    int idx = blockIdx.x * 256 + threadIdx.x;
    int k = idx >> 9, n = idx & 511;
    int m = ((2 * n + 1) * k) & 2047;
    float ang = (float)m * 3.06796157577128218e-03f;  // pi/1024
    D[idx] = f2bf(2.0f * cosf(ang));
}

// ------------- Stage 1 (fused cvt, v2 ledger): sT[l][h] = bf16( (X @ D^T)[h][l] ) -------------
// 8-phase 256^2; A (X fp32) reg-staged with 4-phase forced-retire lead:
//   issue A(T+2) at T q0/q1; cvt+ds_write A(T+1) at T q2/q3.
// Per-iter FIFO: q0 [A(T+2,h0)x4, B(T+1,h0)x2], q1 [A(T+2,h1)x4, B(T+1,h1)x2].
// Steady waits: q0 vmcnt(6), q1 vmcnt(6); tail T=6 q1 vmcnt(2); peeled T=7: 2,0.
__global__ __launch_bounds__(512) void k_s1f2(
        const float* __restrict__ X,
        const unsigned short* __restrict__ D,
        unsigned short* __restrict__ sT) {
    __shared__ __align__(16) char LDS[131072];   // A: 2x32KB @0 | B: 2x32KB @65536

    const int bid = blockIdx.x;
    const int nb  = (bid & 7) * (NWG8 / 8) + (bid >> 3);
    const int bc = nb >> 2, mt = (nb >> 1) & 1, nt = nb & 1;
    const int mA0 = mt * 256, nB0 = nt * 256;
    const float* Ximg = X + (size_t)bc * NPIX * NPIX;

    const int tid  = threadIdx.x;
    const int lane = tid & 63;
    const int wid  = tid >> 6;
    const int wr = wid >> 2, wc = wid & 3;     // 2x4 wave grid; wave C = 128x64
    const int rm = lane & 15;
    const int kq = lane >> 4;

    const int rpA = tid >> 2, qA = tid & 3;    // A-staging: row-slot, 16-float quarter
    const int rowLocalBase = ((rpA >> 6) << 7) + (rpA & 63);

    f32x4 acc[8][4] = {};
    bf16x8 a[4][2], b0[2][2], b1[2][2];
    float4 av[2][2][4];                        // [tile parity][half][4 x float4]

    auto issueA = [&](int kt, int H, float4 (&v)[4]) {
        const float* src = Ximg + (size_t)(mA0 + rowLocalBase + H * 64) * NPIX
                                + kt * 64 + qA * 16;
        v[0] = *(const float4*)(src + 0);
        v[1] = *(const float4*)(src + 4);
        v[2] = *(const float4*)(src + 8);
        v[3] = *(const float4*)(src + 12);
    };
    auto writeAh = [&](int p, int H, const float4 (&v)[4]) {
        char* dst = LDS + p * 32768 + H * 16384 + rpA * 128;
        u16x8 w0, w1;
        w0[0] = f2bf(v[0].x); w0[1] = f2bf(v[0].y); w0[2] = f2bf(v[0].z); w0[3] = f2bf(v[0].w);
        w0[4] = f2bf(v[1].x); w0[5] = f2bf(v[1].y); w0[6] = f2bf(v[1].z); w0[7] = f2bf(v[1].w);
        w1[0] = f2bf(v[2].x); w1[1] = f2bf(v[2].y); w1[2] = f2bf(v[2].z); w1[3] = f2bf(v[2].w);
        w1[4] = f2bf(v[3].x); w1[5] = f2bf(v[3].y); w1[6] = f2bf(v[3].z); w1[7] = f2bf(v[3].w);
        *(u16x8*)(dst + (((qA * 2 + 0) ^ (rpA & 7)) * 16)) = w0;
        *(u16x8*)(dst + (((qA * 2 + 1) ^ (rpA & 7)) * 16)) = w1;
    };
    auto stageB = [&](int kt, int p, int H) {
        char* dst = LDS + 65536 + p * 32768 + H * 16384;
        #pragma unroll
        for (int it = 0; it < 2; ++it) {
            int c = it * 512 + tid;
            int rp = c >> 3, g = c & 7;
            int gs = g ^ (rp & 7);
            int row = ((rp >> 5) << 6) + H * 32 + (rp & 31);
            GLD16(D + (size_t)(nB0 + row) * NPIX + kt * 64 + gs * 8, dst + c * 16);
        }
    };
    auto readA = [&](int p, int mh) {
        const char* base = LDS + p * 32768 + mh * 16384;
        #pragma unroll
        for (int f = 0; f < 4; ++f) {
            int rp = wr * 64 + f * 16 + rm;
            #pragma unroll
            for (int ks = 0; ks < 2; ++ks) {
                int slot = (ks * 4 + kq) ^ (rm & 7);
                a[f][ks] = *(const bf16x8*)(base + rp * 128 + slot * 16);
            }
        }
    };
    auto readB = [&](int p, int nh, bf16x8 (&b)[2][2]) {
        const char* base = LDS + 65536 + p * 32768 + nh * 16384;
        #pragma unroll
        for (int jj = 0; jj < 2; ++jj) {
            int rp = wc * 32 + jj * 16 + rm;
            #pragma unroll
            for (int ks = 0; ks < 2; ++ks) {
                int slot = (ks * 4 + kq) ^ (rm & 7);
                b[jj][ks] = *(const bf16x8*)(base + rp * 128 + slot * 16);
            }
        }
    };
    auto mma = [&](int mh, int nh, bf16x8 (&b)[2][2]) {
        __builtin_amdgcn_s_setprio(1);
        #pragma unroll
        for (int f = 0; f < 4; ++f)
            #pragma unroll
            for (int jj = 0; jj < 2; ++jj)
                #pragma unroll
                for (int ks = 0; ks < 2; ++ks)
                    acc[mh * 4 + f][nh * 2 + jj] = __builtin_amdgcn_mfma_f32_16x16x32_bf16(
                        a[f][ks], b[jj][ks], acc[mh * 4 + f][nh * 2 + jj], 0, 0, 0);
        __builtin_amdgcn_s_setprio(0);
    };

    // --- prologue: A(0) -> LDS slot 0; then steady-pattern issue [A1h0,B0h0][A1h1,B0h1] ---
    issueA(0, 0, av[0][0]);
    issueA(0, 1, av[0][1]);
    asm volatile("s_waitcnt vmcnt(0)" ::: "memory"); SB0();
    writeAh(0, 0, av[0][0]);
    writeAh(0, 1, av[0][1]);
    issueA(1, 0, av[1][0]); SB0();
    stageB(0, 0, 0);        SB0();
    issueA(1, 1, av[1][1]); SB0();
    stageB(0, 0, 1);        SB0();
    // outstanding: [A1h0x4, B0h0x2, A1h1x4, B0h1x2] = 12  (exact steady pattern)

    #pragma unroll
    for (int T = 0; T < 7; ++T) {
        const int p = T & 1, pn = p ^ 1;
        // ---- q0: retire A(T+1,h0)+B(T,h0); compute (0,0) ----
        asm volatile("s_waitcnt vmcnt(6)" ::: "memory");
        LGKM0();
        SBAR();
        readA(p, 0); readB(p, 0, b0);
        if (T + 2 < 8) { issueA(T + 2, 0, av[p][0]); }
        SB0();
        stageB(T + 1, pn, 0);
        SB0();
        LGKM0(); mma(0, 0, b0);
        // ---- q1: retire A(T+1,h1)+B(T,h1); compute (0,1) ----
        if (T < 6) { asm volatile("s_waitcnt vmcnt(6)" ::: "memory"); }
        else       { asm volatile("s_waitcnt vmcnt(2)" ::: "memory"); }
        SBAR();
        readB(p, 1, b1);
        if (T + 2 < 8) { issueA(T + 2, 1, av[p][1]); }
        SB0();
        stageB(T + 1, pn, 1);
        SB0();
        LGKM0(); mma(0, 1, b1);
        // ---- q2: cvt+write A(T+1,h0) (already retired by q0's wait) ----
        SBAR();
        readA(p, 1);
        writeAh(pn, 0, av[pn][0]);
        LGKM0(); mma(1, 0, b0);
        // ---- q3: cvt+write A(T+1,h1) ----
        SBAR();
        writeAh(pn, 1, av[pn][1]);
        mma(1, 1, b1);
    }
    {   // peeled T=7 (slot 1): outstanding entering = [B7h0x2, B7h1x2]
        asm volatile("s_waitcnt vmcnt(2)" ::: "memory");
        LGKM0();
        SBAR();
        readA(1, 0); readB(1, 0, b0); LGKM0(); mma(0, 0, b0);
        asm volatile("s_waitcnt vmcnt(0)" ::: "memory");
        SBAR();
        readB(1, 1, b1); LGKM0(); mma(0, 1, b1);
        SBAR();
        readA(1, 1); LGKM0(); mma(1, 0, b0);
        SBAR();
        mma(1, 1, b1);
    }

    // Transposed bf16 epilogue through the (now dead) 128KB staging LDS.
    SBAR();
    #pragma unroll
    for (int mh = 0; mh < 2; ++mh)
        #pragma unroll
        for (int f = 0; f < 4; ++f) {
            int h_loc = wr * 128 + mh * 64 + f * 16 + kq * 4;
            #pragma unroll
            for (int nh = 0; nh < 2; ++nh)
                #pragma unroll
                for (int jj = 0; jj < 2; ++jj) {
                    int l_loc = wc * 64 + (nh * 2 + jj) * 16 + rm;
                    int byte = (l_loc * 512 + h_loc * 2) ^ ((l_loc & 7) << 4);
                    f32x4 v = acc[mh * 4 + f][nh * 2 + jj];
                    ushort4 w;
                    w.x = f2bf(v[0]); w.y = f2bf(v[1]);
                    w.z = f2bf(v[2]); w.w = f2bf(v[3]);
                    *(ushort4*)(LDS + byte) = w;
                }
        }
    LGKM0(); SBAR();
    unsigned short* Co = sT + (size_t)bc * NPIX * NPIX;
    #pragma unroll
    for (int i = 0; i < 16; ++i) {
        int chunk = i * 512 + tid;
        int l_loc = chunk >> 5, g = chunk & 31;
        int byte = (l_loc * 512 + g * 16) ^ ((l_loc & 7) << 4);
        u16x8 v = *(const u16x8*)(LDS + byte);
        *(u16x8*)&Co[(size_t)(nB0 + l_loc) * NPIX + mA0 + g * 8] = v;
    }
}

// ------------- Stage 2: out[k][l] = (D @ sT^T)[k][l] * 1e-3 (proven 21us, unchanged) -------------
__global__ __launch_bounds__(512) void k_s2g(
        const unsigned short* __restrict__ D,
        const unsigned short* __restrict__ sT,
        float* __restrict__ Cv) {
    __shared__ __align__(16) char LDS[131072];

    const int bid = blockIdx.x;
    const int nb  = (bid & 7) * (NWG8 / 8) + (bid >> 3);
    const int bc = nb >> 2, mt = (nb >> 1) & 1, nt = nb & 1;
    const int mA0 = mt * 256, nB0 = nt * 256;
    const unsigned short* Aimg = D;
    const unsigned short* Bimg = sT + (size_t)bc * NPIX * NPIX;

    const int tid  = threadIdx.x;
    const int lane = tid & 63;
    const int wid  = tid >> 6;
    const int wr = wid >> 2, wc = wid & 3;
    const int rm = lane & 15;
    const int kq = lane >> 4;

    f32x4 acc[8][4] = {};
    bf16x8 a[4][2], b0[2][2], b1[2][2];

    auto stageA = [&](int kt, int p, int H) {
        char* dst = LDS + p * 32768 + H * 16384;
        #pragma unroll
        for (int it = 0; it < 2; ++it) {
            int c = it * 512 + tid;
            int rp = c >> 3, g = c & 7;
            int gs = g ^ (rp & 7);
            int row = ((rp >> 6) << 7) + H * 64 + (rp & 63);
            GLD16(Aimg + (size_t)(mA0 + row) * NPIX + kt * 64 + gs * 8, dst + c * 16);
        }
    };
    auto stageB = [&](int kt, int p, int H) {
        char* dst = LDS + 65536 + p * 32768 + H * 16384;
        #pragma unroll
        for (int it = 0; it < 2; ++it) {
            int c = it * 512 + tid;
            int rp = c >> 3, g = c & 7;
            int gs = g ^ (rp & 7);
            int row = ((rp >> 5) << 6) + H * 32 + (rp & 31);
            GLD16(Bimg + (size_t)(nB0 + row) * NPIX + kt * 64 + gs * 8, dst + c * 16);
        }
    };
    auto readA = [&](int p, int mh) {
        const char* base = LDS + p * 32768 + mh * 16384;
        #pragma unroll
        for (int f = 0; f < 4; ++f) {
            int rp = wr * 64 + f * 16 + rm;
            #pragma unroll
            for (int ks = 0; ks < 2; ++ks) {
                int slot = (ks * 4 + kq) ^ (rm & 7);
                a[f][ks] = *(const bf16x8*)(base + rp * 128 + slot * 16);
            }
        }
    };
    auto readB = [&](int p, int nh, bf16x8 (&b)[2][2]) {
        const char* base = LDS + 65536 + p * 32768 + nh * 16384;
        #pragma unroll
        for (int jj = 0; jj < 2; ++jj) {
            int rp = wc * 32 + jj * 16 + rm;
            #pragma unroll
            for (int ks = 0; ks < 2; ++ks) {
                int slot = (ks * 4 + kq) ^ (rm & 7);
                b[jj][ks] = *(const bf16x8*)(base + rp * 128 + slot * 16);
            }
        }
    };
    auto mma = [&](int mh, int nh, bf16x8 (&b)[2][2]) {
        __builtin_amdgcn_s_setprio(1);
        #pragma unroll
        for (int f = 0; f < 4; ++f)
            #pragma unroll
            for (int jj = 0; jj < 2; ++jj)
                #pragma unroll
                for (int ks = 0; ks < 2; ++ks)
                    acc[mh * 4 + f][nh * 2 + jj] = __builtin_amdgcn_mfma_f32_16x16x32_bf16(
                        a[f][ks], b[jj][ks], acc[mh * 4 + f][nh * 2 + jj], 0, 0, 0);
        __builtin_amdgcn_s_setprio(0);
    };

    stageA(0, 0, 0); stageB(0, 0, 0); stageB(0, 0, 1); stageA(0, 0, 1);

    for (int T = 0; T < 7; ++T) {
        const int p = T & 1, pn = p ^ 1;
        asm volatile("s_waitcnt vmcnt(4)" ::: "memory"); SBAR();
        readA(p, 0); readB(p, 0, b0); stageA(T + 1, pn, 0);
        LGKM0(); mma(0, 0, b0);
        asm volatile("s_waitcnt vmcnt(4)" ::: "memory"); SBAR();
        readB(p, 1, b1); stageB(T + 1, pn, 0);
        LGKM0(); mma(0, 1, b1);
        asm volatile("s_waitcnt vmcnt(4)" ::: "memory"); SBAR();
        readA(p, 1); stageB(T + 1, pn, 1);
        LGKM0(); mma(1, 0, b0);
        SBAR();
        stageA(T + 1, pn, 1);
        mma(1, 1, b1);
    }
    {
        asm volatile("s_waitcnt vmcnt(4)" ::: "memory"); SBAR();
        readA(1, 0); readB(1, 0, b0); LGKM0(); mma(0, 0, b0);
        asm volatile("s_waitcnt vmcnt(2)" ::: "memory"); SBAR();
        readB(1, 1, b1); LGKM0(); mma(0, 1, b1);
        asm volatile("s_waitcnt vmcnt(0)" ::: "memory"); SBAR();
        readA(1, 1); LGKM0(); mma(1, 0, b0);
        SBAR();
        mma(1, 1, b1);
    }

    float* Co = Cv + (size_t)bc * NPIX * NPIX;
    #pragma unroll
    for (int mh = 0; mh < 2; ++mh)
        #pragma unroll
        for (int f = 0; f < 4; ++f) {
            int k_ = mA0 + wr * 128 + mh * 64 + f * 16 + kq * 4;
            #pragma unroll
            for (int nh = 0; nh < 2; ++nh)
                #pragma unroll
                for (int jj = 0; jj < 2; ++jj) {
                    int l_ = nB0 + wc * 64 + (nh * 2 + jj) * 16 + rm;
                    f32x4 v = acc[mh * 4 + f][nh * 2 + jj];
                    #pragma unroll
                    for (int r = 0; r < 4; ++r)
                        Co[(size_t)(k_ + r) * NPIX + l_] = v[r] * 1.0e-3f;
                }
        }
}

extern "C" void kernel_launch(void* const* d_in, const int* in_sizes, int n_in,
                              void* d_out, int out_size, void* d_ws, size_t ws_size,
                              hipStream_t stream) {
    const float* img = (const float*)d_in[0];
    float* out = (float*)d_out;

    unsigned short* D  = (unsigned short*)d_ws;                       // 512 KB
    unsigned short* sT = (unsigned short*)((char*)d_ws + 512 * 1024); // 48 MB

    k_basis<<<dim3(512 * 512 / 256), dim3(256), 0, stream>>>(D);

    // Stage 1 (fused fp32->bf16, 4-phase-lead ledger): sT[l][h] = bf16( (X @ D^T)[h][l] )
    k_s1f2<<<dim3(NWG8), dim3(512), 0, stream>>>(img, D, sT);

    // Stage 2: out[k][l] = (D @ sT^T)[k][l] * 1e-3
    k_s2g<<<dim3(NWG8), dim3(512), 0, stream>>>(D, sT, out);
}

// Round 9
// 118.717 us; speedup vs baseline: 1.1970x; 1.1970x over previous
//
#include <hip/hip_runtime.h>
#include <hip/hip_bf16.h>
#include <stdint.h>

#define NPIX 512
#define NBC  96
#define NWG8 (NBC * 4)      // 384 blocks: 96 images x 2x2 tiles of 256^2

typedef __attribute__((ext_vector_type(8))) short bf16x8;
typedef __attribute__((ext_vector_type(4))) float f32x4;
typedef __attribute__((ext_vector_type(8))) unsigned short u16x8;

__device__ __forceinline__ unsigned short f2bf(float f) {
    __hip_bfloat16 h = __float2bfloat16(f);
    union { __hip_bfloat16 h; unsigned short u; } v;
    v.h = h;
    return v.u;
}

#define GLD16(g, l) __builtin_amdgcn_global_load_lds( \
    (const __attribute__((address_space(1))) void*)(const void*)(g), \
    (__attribute__((address_space(3))) void*)(void*)(l), 16, 0, 0)

#define SBAR() do { __builtin_amdgcn_sched_barrier(0); \
                    __builtin_amdgcn_s_barrier(); \
                    __builtin_amdgcn_sched_barrier(0); } while (0)
#define LGKM0() do { asm volatile("s_waitcnt lgkmcnt(0)" ::: "memory"); \
                     __builtin_amdgcn_sched_barrier(0); } while (0)
#define SB0() __builtin_amdgcn_sched_barrier(0)

// ---------------- D basis: D[k][n] = bf16(2*cos(pi*(2n+1)*k/1024)) ----------------
__global__ void k_basis(unsigned short* __restrict__ D) {
    int idx = blockIdx.x * 256 + threadIdx.x;
    int k = idx >> 9, n = idx & 511;
    int m = ((2 * n + 1) * k) & 2047;
    float ang = (float)m * 3.06796157577128218e-03f;  // pi/1024
    D[idx] = f2bf(2.0f * cosf(ang));
}

// ------------- Stage 1 (fused cvt, v3 ledger): sT[l][h] = bf16( (X @ D^T)[h][l] ) -------------
// 8-phase 256^2; A (X fp32) reg-staged with a 4-PHASE forced-retire lead and only ONE
// tile in flight (32 VGPRs): issue A(T+2,h) at T q2/q3 (right after the ds_write of
// A(T+1,h) frees av), write A(T+2,h) at T+1 q2/q3.
// Per-iter FIFO: q0 B(T+1,h0)x2 | q1 B(T+1,h1)x2 | q2 A(T+2,h0)x4 | q3 A(T+2,h1)x4.
// Steady waits: q0 vmcnt(10), q1 vmcnt(10), q2 vmcnt(8), q3 vmcnt(8).
// Tail: T=6 q3 vmcnt(4); peeled T=7: q0 vmcnt(2), q1 vmcnt(0).
__global__ __launch_bounds__(512) void k_s1f3(
        const float* __restrict__ X,
        const unsigned short* __restrict__ D,
        unsigned short* __restrict__ sT) {
    __shared__ __align__(16) char LDS[131072];   // A: 2x32KB @0 | B: 2x32KB @65536

    const int bid = blockIdx.x;
    const int nb  = (bid & 7) * (NWG8 / 8) + (bid >> 3);
    const int bc = nb >> 2, mt = (nb >> 1) & 1, nt = nb & 1;
    const int mA0 = mt * 256, nB0 = nt * 256;
    const float* Ximg = X + (size_t)bc * NPIX * NPIX;

    const int tid  = threadIdx.x;
    const int lane = tid & 63;
    const int wid  = tid >> 6;
    const int wr = wid >> 2, wc = wid & 3;     // 2x4 wave grid; wave C = 128x64
    const int rm = lane & 15;
    const int kq = lane >> 4;

    const int rpA = tid >> 2, qA = tid & 3;    // A-staging: row-slot, 16-float quarter
    const int rowLocalBase = ((rpA >> 6) << 7) + (rpA & 63);

    f32x4 acc[8][4] = {};
    bf16x8 a[4][2], b0[2][2], b1[2][2];
    float4 av0[4], av1[4];                     // ONE half-tile pair in flight (32 VGPR)

    auto issueA = [&](int kt, int H, float4 (&v)[4]) {
        const float* src = Ximg + (size_t)(mA0 + rowLocalBase + H * 64) * NPIX
                                + kt * 64 + qA * 16;
        v[0] = *(const float4*)(src + 0);
        v[1] = *(const float4*)(src + 4);
        v[2] = *(const float4*)(src + 8);
        v[3] = *(const float4*)(src + 12);
    };
    auto writeAh = [&](int p, int H, const float4 (&v)[4]) {
        char* dst = LDS + p * 32768 + H * 16384 + rpA * 128;
        u16x8 w0, w1;
        w0[0] = f2bf(v[0].x); w0[1] = f2bf(v[0].y); w0[2] = f2bf(v[0].z); w0[3] = f2bf(v[0].w);
        w0[4] = f2bf(v[1].x); w0[5] = f2bf(v[1].y); w0[6] = f2bf(v[1].z); w0[7] = f2bf(v[1].w);
        w1[0] = f2bf(v[2].x); w1[1] = f2bf(v[2].y); w1[2] = f2bf(v[2].z); w1[3] = f2bf(v[2].w);
        w1[4] = f2bf(v[3].x); w1[5] = f2bf(v[3].y); w1[6] = f2bf(v[3].z); w1[7] = f2bf(v[3].w);
        *(u16x8*)(dst + (((qA * 2 + 0) ^ (rpA & 7)) * 16)) = w0;
        *(u16x8*)(dst + (((qA * 2 + 1) ^ (rpA & 7)) * 16)) = w1;
    };
    auto stageB = [&](int kt, int p, int H) {
        char* dst = LDS + 65536 + p * 32768 + H * 16384;
        #pragma unroll
        for (int it = 0; it < 2; ++it) {
            int c = it * 512 + tid;
            int rp = c >> 3, g = c & 7;
            int gs = g ^ (rp & 7);
            int row = ((rp >> 5) << 6) + H * 32 + (rp & 31);
            GLD16(D + (size_t)(nB0 + row) * NPIX + kt * 64 + gs * 8, dst + c * 16);
        }
    };
    auto readA = [&](int p, int mh) {
        const char* base = LDS + p * 32768 + mh * 16384;
        #pragma unroll
        for (int f = 0; f < 4; ++f) {
            int rp = wr * 64 + f * 16 + rm;
            #pragma unroll
            for (int ks = 0; ks < 2; ++ks) {
                int slot = (ks * 4 + kq) ^ (rm & 7);
                a[f][ks] = *(const bf16x8*)(base + rp * 128 + slot * 16);
            }
        }
    };
    auto readB = [&](int p, int nh, bf16x8 (&b)[2][2]) {
        const char* base = LDS + 65536 + p * 32768 + nh * 16384;
        #pragma unroll
        for (int jj = 0; jj < 2; ++jj) {
            int rp = wc * 32 + jj * 16 + rm;
            #pragma unroll
            for (int ks = 0; ks < 2; ++ks) {
                int slot = (ks * 4 + kq) ^ (rm & 7);
                b[jj][ks] = *(const bf16x8*)(base + rp * 128 + slot * 16);
            }
        }
    };
    auto mma = [&](int mh, int nh, bf16x8 (&b)[2][2]) {
        __builtin_amdgcn_s_setprio(1);
        #pragma unroll
        for (int f = 0; f < 4; ++f)
            #pragma unroll
            for (int jj = 0; jj < 2; ++jj)
                #pragma unroll
                for (int ks = 0; ks < 2; ++ks)
                    acc[mh * 4 + f][nh * 2 + jj] = __builtin_amdgcn_mfma_f32_16x16x32_bf16(
                        a[f][ks], b[jj][ks], acc[mh * 4 + f][nh * 2 + jj], 0, 0, 0);
        __builtin_amdgcn_s_setprio(0);
    };

    // --- prologue: A(0) -> LDS slot 0; B(0) GLD; A(1) into regs ---
    issueA(0, 0, av0); SB0();
    issueA(0, 1, av1); SB0();
    stageB(0, 0, 0);   SB0();
    stageB(0, 0, 1);   SB0();          // FIFO: [A0h0 4, A0h1 4, B0h0 2, B0h1 2]
    asm volatile("s_waitcnt vmcnt(8)" ::: "memory"); SB0();
    writeAh(0, 0, av0);
    asm volatile("s_waitcnt vmcnt(4)" ::: "memory"); SB0();
    writeAh(0, 1, av1);
    LGKM0();                           // writes drained -> av reusable
    issueA(1, 0, av0); SB0();
    issueA(1, 1, av1); SB0();          // FIFO: [B0h0 2, B0h1 2, A1h0 4, A1h1 4] = 12

    for (int T = 0; T < 7; ++T) {
        const int p = T & 1, pn = p ^ 1;
        // ---- q0: retire B(T,h0); compute (0,0); stage B(T+1,h0) ----
        asm volatile("s_waitcnt vmcnt(10)" ::: "memory");
        SBAR();
        readA(p, 0); readB(p, 0, b0);
        stageB(T + 1, pn, 0);
        LGKM0(); mma(0, 0, b0);
        // ---- q1: retire B(T,h1); compute (0,1); stage B(T+1,h1) ----
        asm volatile("s_waitcnt vmcnt(10)" ::: "memory");
        SBAR();
        readB(p, 1, b1);
        stageB(T + 1, pn, 1);
        LGKM0(); mma(0, 1, b1);
        // ---- q2: retire A(T+1,h0); write it; reissue av0 for A(T+2,h0) ----
        asm volatile("s_waitcnt vmcnt(8)" ::: "memory");
        SBAR();
        readA(p, 1);
        writeAh(pn, 0, av0);
        LGKM0();                       // drain ds_reads + ds_writes (av0 free)
        if (T < 6) { issueA(T + 2, 0, av0); }
        SB0();
        mma(1, 0, b0);
        // ---- q3: retire A(T+1,h1); write it; reissue av1 for A(T+2,h1) ----
        if (T < 6) { asm volatile("s_waitcnt vmcnt(8)" ::: "memory"); }
        else       { asm volatile("s_waitcnt vmcnt(4)" ::: "memory"); }
        SBAR();
        writeAh(pn, 1, av1);
        LGKM0();                       // av1 free
        if (T < 6) { issueA(T + 2, 1, av1); }
        SB0();
        mma(1, 1, b1);
    }
    {   // peeled T=7 (p=1): outstanding entering = [B7h0 2, B7h1 2]
        asm volatile("s_waitcnt vmcnt(2)" ::: "memory");
        SBAR();
        readA(1, 0); readB(1, 0, b0); LGKM0(); mma(0, 0, b0);
        asm volatile("s_waitcnt vmcnt(0)" ::: "memory");
        SBAR();
        readB(1, 1, b1); LGKM0(); mma(0, 1, b1);
        SBAR();
        readA(1, 1); LGKM0(); mma(1, 0, b0);
        SBAR();
        mma(1, 1, b1);
    }

    // Transposed bf16 epilogue through the (now dead) 128KB staging LDS.
    SBAR();
    #pragma unroll
    for (int mh = 0; mh < 2; ++mh)
        #pragma unroll
        for (int f = 0; f < 4; ++f) {
            int h_loc = wr * 128 + mh * 64 + f * 16 + kq * 4;
            #pragma unroll
            for (int nh = 0; nh < 2; ++nh)
                #pragma unroll
                for (int jj = 0; jj < 2; ++jj) {
                    int l_loc = wc * 64 + (nh * 2 + jj) * 16 + rm;
                    int byte = (l_loc * 512 + h_loc * 2) ^ ((l_loc & 7) << 4);
                    f32x4 v = acc[mh * 4 + f][nh * 2 + jj];
                    ushort4 w;
                    w.x = f2bf(v[0]); w.y = f2bf(v[1]);
                    w.z = f2bf(v[2]); w.w = f2bf(v[3]);
                    *(ushort4*)(LDS + byte) = w;
                }
        }
    LGKM0(); SBAR();
    unsigned short* Co = sT + (size_t)bc * NPIX * NPIX;
    #pragma unroll
    for (int i = 0; i < 16; ++i) {
        int chunk = i * 512 + tid;
        int l_loc = chunk >> 5, g = chunk & 31;
        int byte = (l_loc * 512 + g * 16) ^ ((l_loc & 7) << 4);
        u16x8 v = *(const u16x8*)(LDS + byte);
        *(u16x8*)&Co[(size_t)(nB0 + l_loc) * NPIX + mA0 + g * 8] = v;
    }
}

// ------------- Stage 2: out[k][l] = (D @ sT^T)[k][l] * 1e-3 (proven, unchanged) -------------
__global__ __launch_bounds__(512) void k_s2g(
        const unsigned short* __restrict__ D,
        const unsigned short* __restrict__ sT,
        float* __restrict__ Cv) {
    __shared__ __align__(16) char LDS[131072];

    const int bid = blockIdx.x;
    const int nb  = (bid & 7) * (NWG8 / 8) + (bid >> 3);
    const int bc = nb >> 2, mt = (nb >> 1) & 1, nt = nb & 1;
    const int mA0 = mt * 256, nB0 = nt * 256;
    const unsigned short* Aimg = D;
    const unsigned short* Bimg = sT + (size_t)bc * NPIX * NPIX;

    const int tid  = threadIdx.x;
    const int lane = tid & 63;
    const int wid  = tid >> 6;
    const int wr = wid >> 2, wc = wid & 3;
    const int rm = lane & 15;
    const int kq = lane >> 4;

    f32x4 acc[8][4] = {};
    bf16x8 a[4][2], b0[2][2], b1[2][2];

    auto stageA = [&](int kt, int p, int H) {
        char* dst = LDS + p * 32768 + H * 16384;
        #pragma unroll
        for (int it = 0; it < 2; ++it) {
            int c = it * 512 + tid;
            int rp = c >> 3, g = c & 7;
            int gs = g ^ (rp & 7);
            int row = ((rp >> 6) << 7) + H * 64 + (rp & 63);
            GLD16(Aimg + (size_t)(mA0 + row) * NPIX + kt * 64 + gs * 8, dst + c * 16);
        }
    };
    auto stageB = [&](int kt, int p, int H) {
        char* dst = LDS + 65536 + p * 32768 + H * 16384;
        #pragma unroll
        for (int it = 0; it < 2; ++it) {
            int c = it * 512 + tid;
            int rp = c >> 3, g = c & 7;
            int gs = g ^ (rp & 7);
            int row = ((rp >> 5) << 6) + H * 32 + (rp & 31);
            GLD16(Bimg + (size_t)(nB0 + row) * NPIX + kt * 64 + gs * 8, dst + c * 16);
        }
    };
    auto readA = [&](int p, int mh) {
        const char* base = LDS + p * 32768 + mh * 16384;
        #pragma unroll
        for (int f = 0; f < 4; ++f) {
            int rp = wr * 64 + f * 16 + rm;
            #pragma unroll
            for (int ks = 0; ks < 2; ++ks) {
                int slot = (ks * 4 + kq) ^ (rm & 7);
                a[f][ks] = *(const bf16x8*)(base + rp * 128 + slot * 16);
            }
        }
    };
    auto readB = [&](int p, int nh, bf16x8 (&b)[2][2]) {
        const char* base = LDS + 65536 + p * 32768 + nh * 16384;
        #pragma unroll
        for (int jj = 0; jj < 2; ++jj) {
            int rp = wc * 32 + jj * 16 + rm;
            #pragma unroll
            for (int ks = 0; ks < 2; ++ks) {
                int slot = (ks * 4 + kq) ^ (rm & 7);
                b[jj][ks] = *(const bf16x8*)(base + rp * 128 + slot * 16);
            }
        }
    };
    auto mma = [&](int mh, int nh, bf16x8 (&b)[2][2]) {
        __builtin_amdgcn_s_setprio(1);
        #pragma unroll
        for (int f = 0; f < 4; ++f)
            #pragma unroll
            for (int jj = 0; jj < 2; ++jj)
                #pragma unroll
                for (int ks = 0; ks < 2; ++ks)
                    acc[mh * 4 + f][nh * 2 + jj] = __builtin_amdgcn_mfma_f32_16x16x32_bf16(
                        a[f][ks], b[jj][ks], acc[mh * 4 + f][nh * 2 + jj], 0, 0, 0);
        __builtin_amdgcn_s_setprio(0);
    };

    stageA(0, 0, 0); stageB(0, 0, 0); stageB(0, 0, 1); stageA(0, 0, 1);

    for (int T = 0; T < 7; ++T) {
        const int p = T & 1, pn = p ^ 1;
        asm volatile("s_waitcnt vmcnt(4)" ::: "memory"); SBAR();
        readA(p, 0); readB(p, 0, b0); stageA(T + 1, pn, 0);
        LGKM0(); mma(0, 0, b0);
        asm volatile("s_waitcnt vmcnt(4)" ::: "memory"); SBAR();
        readB(p, 1, b1); stageB(T + 1, pn, 0);
        LGKM0(); mma(0, 1, b1);
        asm volatile("s_waitcnt vmcnt(4)" ::: "memory"); SBAR();
        readA(p, 1); stageB(T + 1, pn, 1);
        LGKM0(); mma(1, 0, b0);
        SBAR();
        stageA(T + 1, pn, 1);
        mma(1, 1, b1);
    }
    {
        asm volatile("s_waitcnt vmcnt(4)" ::: "memory"); SBAR();
        readA(1, 0); readB(1, 0, b0); LGKM0(); mma(0, 0, b0);
        asm volatile("s_waitcnt vmcnt(2)" ::: "memory"); SBAR();
        readB(1, 1, b1); LGKM0(); mma(0, 1, b1);
        asm volatile("s_waitcnt vmcnt(0)" ::: "memory"); SBAR();
        readA(1, 1); LGKM0(); mma(1, 0, b0);
        SBAR();
        mma(1, 1, b1);
    }

    float* Co = Cv + (size_t)bc * NPIX * NPIX;
    #pragma unroll
    for (int mh = 0; mh < 2; ++mh)
        #pragma unroll
        for (int f = 0; f < 4; ++f) {
            int k_ = mA0 + wr * 128 + mh * 64 + f * 16 + kq * 4;
            #pragma unroll
            for (int nh = 0; nh < 2; ++nh)
                #pragma unroll
                for (int jj = 0; jj < 2; ++jj) {
                    int l_ = nB0 + wc * 64 + (nh * 2 + jj) * 16 + rm;
                    f32x4 v = acc[mh * 4 + f][nh * 2 + jj];
                    #pragma unroll
                    for (int r = 0; r < 4; ++r)
                        Co[(size_t)(k_ + r) * NPIX + l_] = v[r] * 1.0e-3f;
                }
        }
}

extern "C" void kernel_launch(void* const* d_in, const int* in_sizes, int n_in,
                              void* d_out, int out_size, void* d_ws, size_t ws_size,
                              hipStream_t stream) {
    const float* img = (const float*)d_in[0];
    float* out = (float*)d_out;

    unsigned short* D  = (unsigned short*)d_ws;                       // 512 KB
    unsigned short* sT = (unsigned short*)((char*)d_ws + 512 * 1024); // 48 MB

    k_basis<<<dim3(512 * 512 / 256), dim3(256), 0, stream>>>(D);

    // Stage 1 (fused fp32->bf16, 4-phase lead, 1 tile in flight): sT[l][h]
    k_s1f3<<<dim3(NWG8), dim3(512), 0, stream>>>(img, D, sT);

    // Stage 2: out[k][l] = (D @ sT^T)[k][l] * 1e-3
    k_s2g<<<dim3(NWG8), dim3(512), 0, stream>>>(D, sT, out);
}

// Round 10
// 110.505 us; speedup vs baseline: 1.2860x; 1.0743x over previous
//
#include <hip/hip_runtime.h>
#include <hip/hip_bf16.h>
#include <stdint.h>

#define NPIX 512
#define NBC  96
#define NWG8 (NBC * 4)      // 384 blocks: 96 images x 2x2 tiles of 256^2

typedef __attribute__((ext_vector_type(8))) short bf16x8;
typedef __attribute__((ext_vector_type(4))) float f32x4;
typedef __attribute__((ext_vector_type(8))) unsigned short u16x8;

__device__ __forceinline__ unsigned short f2bf(float f) {
    __hip_bfloat16 h = __float2bfloat16(f);
    union { __hip_bfloat16 h; unsigned short u; } v;
    v.h = h;
    return v.u;
}

#define GLD16(g, l) __builtin_amdgcn_global_load_lds( \
    (const __attribute__((address_space(1))) void*)(const void*)(g), \
    (__attribute__((address_space(3))) void*)(void*)(l), 16, 0, 0)

#define SBAR() do { __builtin_amdgcn_sched_barrier(0); \
                    __builtin_amdgcn_s_barrier(); \
                    __builtin_amdgcn_sched_barrier(0); } while (0)
#define LGKM0() do { asm volatile("s_waitcnt lgkmcnt(0)" ::: "memory"); \
                     __builtin_amdgcn_sched_barrier(0); } while (0)

// ---------------- D basis: D[k][n] = bf16(2*cos(pi*(2n+1)*k/1024)) ----------------
__global__ void k_basis(unsigned short* __restrict__ D) {
    int idx = blockIdx.x * 256 + threadIdx.x;
    int k = idx >> 9, n = idx & 511;
    int m = ((2 * n + 1) * k) & 2047;
    float ang = (float)m * 3.06796157577128218e-03f;  // pi/1024
    D[idx] = f2bf(2.0f * cosf(ang));
}

// ---------------- cvt: X fp32 -> bf16, 16 elems/thread ----------------
__global__ __launch_bounds__(256) void k_cvt(const float* __restrict__ X,
                                             unsigned short* __restrict__ Xbf) {
    size_t t = (size_t)blockIdx.x * 256 + threadIdx.x;
    const float4* src = (const float4*)X + t * 4;
    float4 a = src[0], b = src[1], c = src[2], d = src[3];
    u16x8 w0, w1;
    w0[0] = f2bf(a.x); w0[1] = f2bf(a.y); w0[2] = f2bf(a.z); w0[3] = f2bf(a.w);
    w0[4] = f2bf(b.x); w0[5] = f2bf(b.y); w0[6] = f2bf(b.z); w0[7] = f2bf(b.w);
    w1[0] = f2bf(c.x); w1[1] = f2bf(c.y); w1[2] = f2bf(c.z); w1[3] = f2bf(c.w);
    w1[4] = f2bf(d.x); w1[5] = f2bf(d.y); w1[6] = f2bf(d.z); w1[7] = f2bf(d.w);
    u16x8* dst = (u16x8*)Xbf + t * 2;
    dst[0] = w0;
    dst[1] = w1;
}

// ------------- Stage 1 (operand-swapped): sT[l][h] = sum_n D[l][n] * Xbf[h][n] -------------
// EXACT clone of the proven k_s2g loop: A = D (shared, L2-hot, like s2g), B = Xbf.
// C[l][h] lands row-major = sT directly -> direct bf16 stores, no transposed epilogue.
__global__ __launch_bounds__(512) void k_s1n(
        const unsigned short* __restrict__ D,
        const unsigned short* __restrict__ Xbf,
        unsigned short* __restrict__ sT) {
    __shared__ __align__(16) char LDS[131072];

    const int bid = blockIdx.x;
    const int nb  = (bid & 7) * (NWG8 / 8) + (bid >> 3);
    const int bc = nb >> 2, mt = (nb >> 1) & 1, nt = nb & 1;
    const int mA0 = mt * 256, nB0 = nt * 256;      // mA0: D rows (l), nB0: Xbf rows (h)
    const unsigned short* Aimg = D;                // shared basis, stride 0
    const unsigned short* Bimg = Xbf + (size_t)bc * NPIX * NPIX;

    const int tid  = threadIdx.x;
    const int lane = tid & 63;
    const int wid  = tid >> 6;
    const int wr = wid >> 2, wc = wid & 3;
    const int rm = lane & 15;
    const int kq = lane >> 4;

    f32x4 acc[8][4] = {};
    bf16x8 a[4][2], b0[2][2], b1[2][2];

    auto stageA = [&](int kt, int p, int H) {
        char* dst = LDS + p * 32768 + H * 16384;
        #pragma unroll
        for (int it = 0; it < 2; ++it) {
            int c = it * 512 + tid;
            int rp = c >> 3, g = c & 7;
            int gs = g ^ (rp & 7);
            int row = ((rp >> 6) << 7) + H * 64 + (rp & 63);
            GLD16(Aimg + (size_t)(mA0 + row) * NPIX + kt * 64 + gs * 8, dst + c * 16);
        }
    };
    auto stageB = [&](int kt, int p, int H) {
        char* dst = LDS + 65536 + p * 32768 + H * 16384;
        #pragma unroll
        for (int it = 0; it < 2; ++it) {
            int c = it * 512 + tid;
            int rp = c >> 3, g = c & 7;
            int gs = g ^ (rp & 7);
            int row = ((rp >> 5) << 6) + H * 32 + (rp & 31);
            GLD16(Bimg + (size_t)(nB0 + row) * NPIX + kt * 64 + gs * 8, dst + c * 16);
        }
    };
    auto readA = [&](int p, int mh) {
        const char* base = LDS + p * 32768 + mh * 16384;
        #pragma unroll
        for (int f = 0; f < 4; ++f) {
            int rp = wr * 64 + f * 16 + rm;
            #pragma unroll
            for (int ks = 0; ks < 2; ++ks) {
                int slot = (ks * 4 + kq) ^ (rm & 7);
                a[f][ks] = *(const bf16x8*)(base + rp * 128 + slot * 16);
            }
        }
    };
    auto readB = [&](int p, int nh, bf16x8 (&b)[2][2]) {
        const char* base = LDS + 65536 + p * 32768 + nh * 16384;
        #pragma unroll
        for (int jj = 0; jj < 2; ++jj) {
            int rp = wc * 32 + jj * 16 + rm;
            #pragma unroll
            for (int ks = 0; ks < 2; ++ks) {
                int slot = (ks * 4 + kq) ^ (rm & 7);
                b[jj][ks] = *(const bf16x8*)(base + rp * 128 + slot * 16);
            }
        }
    };
    auto mma = [&](int mh, int nh, bf16x8 (&b)[2][2]) {
        __builtin_amdgcn_s_setprio(1);
        #pragma unroll
        for (int f = 0; f < 4; ++f)
            #pragma unroll
            for (int jj = 0; jj < 2; ++jj)
                #pragma unroll
                for (int ks = 0; ks < 2; ++ks)
                    acc[mh * 4 + f][nh * 2 + jj] = __builtin_amdgcn_mfma_f32_16x16x32_bf16(
                        a[f][ks], b[jj][ks], acc[mh * 4 + f][nh * 2 + jj], 0, 0, 0);
        __builtin_amdgcn_s_setprio(0);
    };

    stageA(0, 0, 0); stageB(0, 0, 0); stageB(0, 0, 1); stageA(0, 0, 1);

    for (int T = 0; T < 7; ++T) {
        const int p = T & 1, pn = p ^ 1;
        asm volatile("s_waitcnt vmcnt(4)" ::: "memory"); SBAR();
        readA(p, 0); readB(p, 0, b0); stageA(T + 1, pn, 0);
        LGKM0(); mma(0, 0, b0);
        asm volatile("s_waitcnt vmcnt(4)" ::: "memory"); SBAR();
        readB(p, 1, b1); stageB(T + 1, pn, 0);
        LGKM0(); mma(0, 1, b1);
        asm volatile("s_waitcnt vmcnt(4)" ::: "memory"); SBAR();
        readA(p, 1); stageB(T + 1, pn, 1);
        LGKM0(); mma(1, 0, b0);
        SBAR();
        stageA(T + 1, pn, 1);
        mma(1, 1, b1);
    }
    {
        asm volatile("s_waitcnt vmcnt(4)" ::: "memory"); SBAR();
        readA(1, 0); readB(1, 0, b0); LGKM0(); mma(0, 0, b0);
        asm volatile("s_waitcnt vmcnt(2)" ::: "memory"); SBAR();
        readB(1, 1, b1); LGKM0(); mma(0, 1, b1);
        asm volatile("s_waitcnt vmcnt(0)" ::: "memory"); SBAR();
        readA(1, 1); LGKM0(); mma(1, 0, b0);
        SBAR();
        mma(1, 1, b1);
    }

    // Direct bf16 epilogue: C[l][h] row-major IS sT.
    unsigned short* Co = sT + (size_t)bc * NPIX * NPIX;
    #pragma unroll
    for (int mh = 0; mh < 2; ++mh)
        #pragma unroll
        for (int f = 0; f < 4; ++f) {
            int l_ = mA0 + wr * 128 + mh * 64 + f * 16 + kq * 4;
            #pragma unroll
            for (int nh = 0; nh < 2; ++nh)
                #pragma unroll
                for (int jj = 0; jj < 2; ++jj) {
                    int h_ = nB0 + wc * 64 + (nh * 2 + jj) * 16 + rm;
                    f32x4 v = acc[mh * 4 + f][nh * 2 + jj];
                    #pragma unroll
                    for (int r = 0; r < 4; ++r)
                        Co[(size_t)(l_ + r) * NPIX + h_] = f2bf(v[r]);
                }
        }
}

// ------------- Stage 2: out[k][l] = (D @ sT^T)[k][l] * 1e-3 (proven, unchanged) -------------
__global__ __launch_bounds__(512) void k_s2g(
        const unsigned short* __restrict__ D,
        const unsigned short* __restrict__ sT,
        float* __restrict__ Cv) {
    __shared__ __align__(16) char LDS[131072];

    const int bid = blockIdx.x;
    const int nb  = (bid & 7) * (NWG8 / 8) + (bid >> 3);
    const int bc = nb >> 2, mt = (nb >> 1) & 1, nt = nb & 1;
    const int mA0 = mt * 256, nB0 = nt * 256;
    const unsigned short* Aimg = D;
    const unsigned short* Bimg = sT + (size_t)bc * NPIX * NPIX;

    const int tid  = threadIdx.x;
    const int lane = tid & 63;
    const int wid  = tid >> 6;
    const int wr = wid >> 2, wc = wid & 3;
    const int rm = lane & 15;
    const int kq = lane >> 4;

    f32x4 acc[8][4] = {};
    bf16x8 a[4][2], b0[2][2], b1[2][2];

    auto stageA = [&](int kt, int p, int H) {
        char* dst = LDS + p * 32768 + H * 16384;
        #pragma unroll
        for (int it = 0; it < 2; ++it) {
            int c = it * 512 + tid;
            int rp = c >> 3, g = c & 7;
            int gs = g ^ (rp & 7);
            int row = ((rp >> 6) << 7) + H * 64 + (rp & 63);
            GLD16(Aimg + (size_t)(mA0 + row) * NPIX + kt * 64 + gs * 8, dst + c * 16);
        }
    };
    auto stageB = [&](int kt, int p, int H) {
        char* dst = LDS + 65536 + p * 32768 + H * 16384;
        #pragma unroll
        for (int it = 0; it < 2; ++it) {
            int c = it * 512 + tid;
            int rp = c >> 3, g = c & 7;
            int gs = g ^ (rp & 7);
            int row = ((rp >> 5) << 6) + H * 32 + (rp & 31);
            GLD16(Bimg + (size_t)(nB0 + row) * NPIX + kt * 64 + gs * 8, dst + c * 16);
        }
    };
    auto readA = [&](int p, int mh) {
        const char* base = LDS + p * 32768 + mh * 16384;
        #pragma unroll
        for (int f = 0; f < 4; ++f) {
            int rp = wr * 64 + f * 16 + rm;
            #pragma unroll
            for (int ks = 0; ks < 2; ++ks) {
                int slot = (ks * 4 + kq) ^ (rm & 7);
                a[f][ks] = *(const bf16x8*)(base + rp * 128 + slot * 16);
            }
        }
    };
    auto readB = [&](int p, int nh, bf16x8 (&b)[2][2]) {
        const char* base = LDS + 65536 + p * 32768 + nh * 16384;
        #pragma unroll
        for (int jj = 0; jj < 2; ++jj) {
            int rp = wc * 32 + jj * 16 + rm;
            #pragma unroll
            for (int ks = 0; ks < 2; ++ks) {
                int slot = (ks * 4 + kq) ^ (rm & 7);
                b[jj][ks] = *(const bf16x8*)(base + rp * 128 + slot * 16);
            }
        }
    };
    auto mma = [&](int mh, int nh, bf16x8 (&b)[2][2]) {
        __builtin_amdgcn_s_setprio(1);
        #pragma unroll
        for (int f = 0; f < 4; ++f)
            #pragma unroll
            for (int jj = 0; jj < 2; ++jj)
                #pragma unroll
                for (int ks = 0; ks < 2; ++ks)
                    acc[mh * 4 + f][nh * 2 + jj] = __builtin_amdgcn_mfma_f32_16x16x32_bf16(
                        a[f][ks], b[jj][ks], acc[mh * 4 + f][nh * 2 + jj], 0, 0, 0);
        __builtin_amdgcn_s_setprio(0);
    };

    stageA(0, 0, 0); stageB(0, 0, 0); stageB(0, 0, 1); stageA(0, 0, 1);

    for (int T = 0; T < 7; ++T) {
        const int p = T & 1, pn = p ^ 1;
        asm volatile("s_waitcnt vmcnt(4)" ::: "memory"); SBAR();
        readA(p, 0); readB(p, 0, b0); stageA(T + 1, pn, 0);
        LGKM0(); mma(0, 0, b0);
        asm volatile("s_waitcnt vmcnt(4)" ::: "memory"); SBAR();
        readB(p, 1, b1); stageB(T + 1, pn, 0);
        LGKM0(); mma(0, 1, b1);
        asm volatile("s_waitcnt vmcnt(4)" ::: "memory"); SBAR();
        readA(p, 1); stageB(T + 1, pn, 1);
        LGKM0(); mma(1, 0, b0);
        SBAR();
        stageA(T + 1, pn, 1);
        mma(1, 1, b1);
    }
    {
        asm volatile("s_waitcnt vmcnt(4)" ::: "memory"); SBAR();
        readA(1, 0); readB(1, 0, b0); LGKM0(); mma(0, 0, b0);
        asm volatile("s_waitcnt vmcnt(2)" ::: "memory"); SBAR();
        readB(1, 1, b1); LGKM0(); mma(0, 1, b1);
        asm volatile("s_waitcnt vmcnt(0)" ::: "memory"); SBAR();
        readA(1, 1); LGKM0(); mma(1, 0, b0);
        SBAR();
        mma(1, 1, b1);
    }

    float* Co = Cv + (size_t)bc * NPIX * NPIX;
    #pragma unroll
    for (int mh = 0; mh < 2; ++mh)
        #pragma unroll
        for (int f = 0; f < 4; ++f) {
            int k_ = mA0 + wr * 128 + mh * 64 + f * 16 + kq * 4;
            #pragma unroll
            for (int nh = 0; nh < 2; ++nh)
                #pragma unroll
                for (int jj = 0; jj < 2; ++jj) {
                    int l_ = nB0 + wc * 64 + (nh * 2 + jj) * 16 + rm;
                    f32x4 v = acc[mh * 4 + f][nh * 2 + jj];
                    #pragma unroll
                    for (int r = 0; r < 4; ++r)
                        Co[(size_t)(k_ + r) * NPIX + l_] = v[r] * 1.0e-3f;
                }
        }
}

extern "C" void kernel_launch(void* const* d_in, const int* in_sizes, int n_in,
                              void* d_out, int out_size, void* d_ws, size_t ws_size,
                              hipStream_t stream) {
    const float* img = (const float*)d_in[0];
    float* out = (float*)d_out;

    const size_t ST_OFF = 512 * 1024;                     // 512 KB for D
    const size_t ST_SZ  = (size_t)NBC * NPIX * NPIX * 2;  // 48 MB
    const size_t XBF_SZ = ST_SZ;

    unsigned short* D  = (unsigned short*)d_ws;
    unsigned short* sT = (unsigned short*)((char*)d_ws + ST_OFF);
    unsigned short* Xbf;
    if (ws_size >= ST_OFF + ST_SZ + XBF_SZ)
        Xbf = (unsigned short*)((char*)d_ws + ST_OFF + ST_SZ);
    else
        Xbf = (unsigned short*)d_out;                     // dead until stage2 overwrites

    k_basis<<<dim3(512 * 512 / 256), dim3(256), 0, stream>>>(D);
    k_cvt<<<dim3((int)((size_t)NBC * NPIX * NPIX / 16 / 256)), dim3(256), 0, stream>>>(img, Xbf);

    // Stage 1 (operand-swapped, s2g-clone): sT[l][h] = sum_n D[l][n]*Xbf[h][n]
    k_s1n<<<dim3(NWG8), dim3(512), 0, stream>>>(D, Xbf, sT);
    // Stage 2: out[k][l] = (D @ sT^T)[k][l] * 1e-3
    k_s2g<<<dim3(NWG8), dim3(512), 0, stream>>>(D, sT, out);
}

// Round 11
// 109.564 us; speedup vs baseline: 1.2970x; 1.0086x over previous
//
#include <hip/hip_runtime.h>
#include <hip/hip_bf16.h>
#include <stdint.h>

#define NPIX 512
#define NBC  96
#define NWG8 (NBC * 4)      // 384 blocks: 96 images x 2x2 tiles of 256^2

typedef __attribute__((ext_vector_type(8))) short bf16x8;
typedef __attribute__((ext_vector_type(4))) float f32x4;
typedef __attribute__((ext_vector_type(8))) unsigned short u16x8;

__device__ __forceinline__ unsigned short f2bf(float f) {
    __hip_bfloat16 h = __float2bfloat16(f);
    union { __hip_bfloat16 h; unsigned short u; } v;
    v.h = h;
    return v.u;
}

#define GLD16(g, l) __builtin_amdgcn_global_load_lds( \
    (const __attribute__((address_space(1))) void*)(const void*)(g), \
    (__attribute__((address_space(3))) void*)(void*)(l), 16, 0, 0)

#define SBAR() do { __builtin_amdgcn_sched_barrier(0); \
                    __builtin_amdgcn_s_barrier(); \
                    __builtin_amdgcn_sched_barrier(0); } while (0)
#define LGKM0() do { asm volatile("s_waitcnt lgkmcnt(0)" ::: "memory"); \
                     __builtin_amdgcn_sched_barrier(0); } while (0)

// ---------------- D basis: D[k][n] = bf16(2*cos(pi*(2n+1)*k/1024)) ----------------
__global__ void k_basis(unsigned short* __restrict__ D) {
    int idx = blockIdx.x * 256 + threadIdx.x;
    int k = idx >> 9, n = idx & 511;
    int m = ((2 * n + 1) * k) & 2047;
    float ang = (float)m * 3.06796157577128218e-03f;  // pi/1024
    D[idx] = f2bf(2.0f * cosf(ang));
}

// ---------------- cvt: X fp32 -> bf16, LANE-CONTIGUOUS (fix 64B-stride mistake) ----------------
// Thread t handles float4 index blk*1024 + q*256 + t: each wave instruction reads
// 64 consecutive float4 (1KB contiguous) and writes 64 consecutive ushort4 (512B).
__global__ __launch_bounds__(256) void k_cvt(const float* __restrict__ X,
                                             unsigned short* __restrict__ Xbf) {
    size_t base = (size_t)blockIdx.x * 1024 + threadIdx.x;   // float4 units
    const float4* src = (const float4*)X;
    ushort4* dst = (ushort4*)Xbf;
    #pragma unroll
    for (int q = 0; q < 4; ++q) {
        size_t i = base + q * 256;
        float4 v = src[i];
        ushort4 w;
        w.x = f2bf(v.x); w.y = f2bf(v.y); w.z = f2bf(v.z); w.w = f2bf(v.w);
        dst[i] = w;
    }
}

// ------------- Stage 1 (operand-swapped): sT[l][h] = sum_n D[l][n] * Xbf[h][n] -------------
// Clone of the proven k_s2g loop: A = D (shared, L2-hot), B = Xbf.
// C[l][h] lands row-major = sT directly -> direct bf16 stores.
__global__ __launch_bounds__(512) void k_s1n(
        const unsigned short* __restrict__ D,
        const unsigned short* __restrict__ Xbf,
        unsigned short* __restrict__ sT) {
    __shared__ __align__(16) char LDS[131072];

    const int bid = blockIdx.x;
    const int nb  = (bid & 7) * (NWG8 / 8) + (bid >> 3);
    const int bc = nb >> 2, mt = (nb >> 1) & 1, nt = nb & 1;
    const int mA0 = mt * 256, nB0 = nt * 256;
    const unsigned short* Aimg = D;
    const unsigned short* Bimg = Xbf + (size_t)bc * NPIX * NPIX;

    const int tid  = threadIdx.x;
    const int lane = tid & 63;
    const int wid  = tid >> 6;
    const int wr = wid >> 2, wc = wid & 3;
    const int rm = lane & 15;
    const int kq = lane >> 4;

    f32x4 acc[8][4] = {};
    bf16x8 a[4][2], b0[2][2], b1[2][2];

    auto stageA = [&](int kt, int p, int H) {
        char* dst = LDS + p * 32768 + H * 16384;
        #pragma unroll
        for (int it = 0; it < 2; ++it) {
            int c = it * 512 + tid;
            int rp = c >> 3, g = c & 7;
            int gs = g ^ (rp & 7);
            int row = ((rp >> 6) << 7) + H * 64 + (rp & 63);
            GLD16(Aimg + (size_t)(mA0 + row) * NPIX + kt * 64 + gs * 8, dst + c * 16);
        }
    };
    auto stageB = [&](int kt, int p, int H) {
        char* dst = LDS + 65536 + p * 32768 + H * 16384;
        #pragma unroll
        for (int it = 0; it < 2; ++it) {
            int c = it * 512 + tid;
            int rp = c >> 3, g = c & 7;
            int gs = g ^ (rp & 7);
            int row = ((rp >> 5) << 6) + H * 32 + (rp & 31);
            GLD16(Bimg + (size_t)(nB0 + row) * NPIX + kt * 64 + gs * 8, dst + c * 16);
        }
    };
    auto readA = [&](int p, int mh) {
        const char* base = LDS + p * 32768 + mh * 16384;
        #pragma unroll
        for (int f = 0; f < 4; ++f) {
            int rp = wr * 64 + f * 16 + rm;
            #pragma unroll
            for (int ks = 0; ks < 2; ++ks) {
                int slot = (ks * 4 + kq) ^ (rm & 7);
                a[f][ks] = *(const bf16x8*)(base + rp * 128 + slot * 16);
            }
        }
    };
    auto readB = [&](int p, int nh, bf16x8 (&b)[2][2]) {
        const char* base = LDS + 65536 + p * 32768 + nh * 16384;
        #pragma unroll
        for (int jj = 0; jj < 2; ++jj) {
            int rp = wc * 32 + jj * 16 + rm;
            #pragma unroll
            for (int ks = 0; ks < 2; ++ks) {
                int slot = (ks * 4 + kq) ^ (rm & 7);
                b[jj][ks] = *(const bf16x8*)(base + rp * 128 + slot * 16);
            }
        }
    };
    auto mma = [&](int mh, int nh, bf16x8 (&b)[2][2]) {
        __builtin_amdgcn_s_setprio(1);
        #pragma unroll
        for (int f = 0; f < 4; ++f)
            #pragma unroll
            for (int jj = 0; jj < 2; ++jj)
                #pragma unroll
                for (int ks = 0; ks < 2; ++ks)
                    acc[mh * 4 + f][nh * 2 + jj] = __builtin_amdgcn_mfma_f32_16x16x32_bf16(
                        a[f][ks], b[jj][ks], acc[mh * 4 + f][nh * 2 + jj], 0, 0, 0);
        __builtin_amdgcn_s_setprio(0);
    };

    stageA(0, 0, 0); stageB(0, 0, 0); stageB(0, 0, 1); stageA(0, 0, 1);

    for (int T = 0; T < 7; ++T) {
        const int p = T & 1, pn = p ^ 1;
        asm volatile("s_waitcnt vmcnt(4)" ::: "memory"); SBAR();
        readA(p, 0); readB(p, 0, b0); stageA(T + 1, pn, 0);
        LGKM0(); mma(0, 0, b0);
        asm volatile("s_waitcnt vmcnt(4)" ::: "memory"); SBAR();
        readB(p, 1, b1); stageB(T + 1, pn, 0);
        LGKM0(); mma(0, 1, b1);
        asm volatile("s_waitcnt vmcnt(4)" ::: "memory"); SBAR();
        readA(p, 1); stageB(T + 1, pn, 1);
        LGKM0(); mma(1, 0, b0);
        SBAR();
        stageA(T + 1, pn, 1);
        mma(1, 1, b1);
    }
    {
        asm volatile("s_waitcnt vmcnt(4)" ::: "memory"); SBAR();
        readA(1, 0); readB(1, 0, b0); LGKM0(); mma(0, 0, b0);
        asm volatile("s_waitcnt vmcnt(2)" ::: "memory"); SBAR();
        readB(1, 1, b1); LGKM0(); mma(0, 1, b1);
        asm volatile("s_waitcnt vmcnt(0)" ::: "memory"); SBAR();
        readA(1, 1); LGKM0(); mma(1, 0, b0);
        SBAR();
        mma(1, 1, b1);
    }

    unsigned short* Co = sT + (size_t)bc * NPIX * NPIX;
    #pragma unroll
    for (int mh = 0; mh < 2; ++mh)
        #pragma unroll
        for (int f = 0; f < 4; ++f) {
            int l_ = mA0 + wr * 128 + mh * 64 + f * 16 + kq * 4;
            #pragma unroll
            for (int nh = 0; nh < 2; ++nh)
                #pragma unroll
                for (int jj = 0; jj < 2; ++jj) {
                    int h_ = nB0 + wc * 64 + (nh * 2 + jj) * 16 + rm;
                    f32x4 v = acc[mh * 4 + f][nh * 2 + jj];
                    #pragma unroll
                    for (int r = 0; r < 4; ++r)
                        Co[(size_t)(l_ + r) * NPIX + h_] = f2bf(v[r]);
                }
        }
}

// ------------- Stage 2: out[k][l] = (D @ sT^T)[k][l] * 1e-3 (proven, unchanged) -------------
__global__ __launch_bounds__(512) void k_s2g(
        const unsigned short* __restrict__ D,
        const unsigned short* __restrict__ sT,
        float* __restrict__ Cv) {
    __shared__ __align__(16) char LDS[131072];

    const int bid = blockIdx.x;
    const int nb  = (bid & 7) * (NWG8 / 8) + (bid >> 3);
    const int bc = nb >> 2, mt = (nb >> 1) & 1, nt = nb & 1;
    const int mA0 = mt * 256, nB0 = nt * 256;
    const unsigned short* Aimg = D;
    const unsigned short* Bimg = sT + (size_t)bc * NPIX * NPIX;

    const int tid  = threadIdx.x;
    const int lane = tid & 63;
    const int wid  = tid >> 6;
    const int wr = wid >> 2, wc = wid & 3;
    const int rm = lane & 15;
    const int kq = lane >> 4;

    f32x4 acc[8][4] = {};
    bf16x8 a[4][2], b0[2][2], b1[2][2];

    auto stageA = [&](int kt, int p, int H) {
        char* dst = LDS + p * 32768 + H * 16384;
        #pragma unroll
        for (int it = 0; it < 2; ++it) {
            int c = it * 512 + tid;
            int rp = c >> 3, g = c & 7;
            int gs = g ^ (rp & 7);
            int row = ((rp >> 6) << 7) + H * 64 + (rp & 63);
            GLD16(Aimg + (size_t)(mA0 + row) * NPIX + kt * 64 + gs * 8, dst + c * 16);
        }
    };
    auto stageB = [&](int kt, int p, int H) {
        char* dst = LDS + 65536 + p * 32768 + H * 16384;
        #pragma unroll
        for (int it = 0; it < 2; ++it) {
            int c = it * 512 + tid;
            int rp = c >> 3, g = c & 7;
            int gs = g ^ (rp & 7);
            int row = ((rp >> 5) << 6) + H * 32 + (rp & 31);
            GLD16(Bimg + (size_t)(nB0 + row) * NPIX + kt * 64 + gs * 8, dst + c * 16);
        }
    };
    auto readA = [&](int p, int mh) {
        const char* base = LDS + p * 32768 + mh * 16384;
        #pragma unroll
        for (int f = 0; f < 4; ++f) {
            int rp = wr * 64 + f * 16 + rm;
            #pragma unroll
            for (int ks = 0; ks < 2; ++ks) {
                int slot = (ks * 4 + kq) ^ (rm & 7);
                a[f][ks] = *(const bf16x8*)(base + rp * 128 + slot * 16);
            }
        }
    };
    auto readB = [&](int p, int nh, bf16x8 (&b)[2][2]) {
        const char* base = LDS + 65536 + p * 32768 + nh * 16384;
        #pragma unroll
        for (int jj = 0; jj < 2; ++jj) {
            int rp = wc * 32 + jj * 16 + rm;
            #pragma unroll
            for (int ks = 0; ks < 2; ++ks) {
                int slot = (ks * 4 + kq) ^ (rm & 7);
                b[jj][ks] = *(const bf16x8*)(base + rp * 128 + slot * 16);
            }
        }
    };
    auto mma = [&](int mh, int nh, bf16x8 (&b)[2][2]) {
        __builtin_amdgcn_s_setprio(1);
        #pragma unroll
        for (int f = 0; f < 4; ++f)
            #pragma unroll
            for (int jj = 0; jj < 2; ++jj)
                #pragma unroll
                for (int ks = 0; ks < 2; ++ks)
                    acc[mh * 4 + f][nh * 2 + jj] = __builtin_amdgcn_mfma_f32_16x16x32_bf16(
                        a[f][ks], b[jj][ks], acc[mh * 4 + f][nh * 2 + jj], 0, 0, 0);
        __builtin_amdgcn_s_setprio(0);
    };

    stageA(0, 0, 0); stageB(0, 0, 0); stageB(0, 0, 1); stageA(0, 0, 1);

    for (int T = 0; T < 7; ++T) {
        const int p = T & 1, pn = p ^ 1;
        asm volatile("s_waitcnt vmcnt(4)" ::: "memory"); SBAR();
        readA(p, 0); readB(p, 0, b0); stageA(T + 1, pn, 0);
        LGKM0(); mma(0, 0, b0);
        asm volatile("s_waitcnt vmcnt(4)" ::: "memory"); SBAR();
        readB(p, 1, b1); stageB(T + 1, pn, 0);
        LGKM0(); mma(0, 1, b1);
        asm volatile("s_waitcnt vmcnt(4)" ::: "memory"); SBAR();
        readA(p, 1); stageB(T + 1, pn, 1);
        LGKM0(); mma(1, 0, b0);
        SBAR();
        stageA(T + 1, pn, 1);
        mma(1, 1, b1);
    }
    {
        asm volatile("s_waitcnt vmcnt(4)" ::: "memory"); SBAR();
        readA(1, 0); readB(1, 0, b0); LGKM0(); mma(0, 0, b0);
        asm volatile("s_waitcnt vmcnt(2)" ::: "memory"); SBAR();
        readB(1, 1, b1); LGKM0(); mma(0, 1, b1);
        asm volatile("s_waitcnt vmcnt(0)" ::: "memory"); SBAR();
        readA(1, 1); LGKM0(); mma(1, 0, b0);
        SBAR();
        mma(1, 1, b1);
    }

    float* Co = Cv + (size_t)bc * NPIX * NPIX;
    #pragma unroll
    for (int mh = 0; mh < 2; ++mh)
        #pragma unroll
        for (int f = 0; f < 4; ++f) {
            int k_ = mA0 + wr * 128 + mh * 64 + f * 16 + kq * 4;
            #pragma unroll
            for (int nh = 0; nh < 2; ++nh)
                #pragma unroll
                for (int jj = 0; jj < 2; ++jj) {
                    int l_ = nB0 + wc * 64 + (nh * 2 + jj) * 16 + rm;
                    f32x4 v = acc[mh * 4 + f][nh * 2 + jj];
                    #pragma unroll
                    for (int r = 0; r < 4; ++r)
                        Co[(size_t)(k_ + r) * NPIX + l_] = v[r] * 1.0e-3f;
                }
        }
}

extern "C" void kernel_launch(void* const* d_in, const int* in_sizes, int n_in,
                              void* d_out, int out_size, void* d_ws, size_t ws_size,
                              hipStream_t stream) {
    const float* img = (const float*)d_in[0];
    float* out = (float*)d_out;

    const size_t ST_OFF = 512 * 1024;                     // 512 KB for D
    const size_t ST_SZ  = (size_t)NBC * NPIX * NPIX * 2;  // 48 MB
    const size_t XBF_SZ = ST_SZ;

    unsigned short* D  = (unsigned short*)d_ws;
    unsigned short* sT = (unsigned short*)((char*)d_ws + ST_OFF);
    unsigned short* Xbf;
    if (ws_size >= ST_OFF + ST_SZ + XBF_SZ)
        Xbf = (unsigned short*)((char*)d_ws + ST_OFF + ST_SZ);
    else
        Xbf = (unsigned short*)d_out;                     // dead until stage2 overwrites

    k_basis<<<dim3(512 * 512 / 256), dim3(256), 0, stream>>>(D);
    // total float4 = 96*512*512/4 = 6.29M; 1024 per block -> 6144 blocks
    k_cvt<<<dim3((int)((size_t)NBC * NPIX * NPIX / 4 / 1024)), dim3(256), 0, stream>>>(img, Xbf);

    // Stage 1 (operand-swapped, s2g-clone): sT[l][h] = sum_n D[l][n]*Xbf[h][n]
    k_s1n<<<dim3(NWG8), dim3(512), 0, stream>>>(D, Xbf, sT);
    // Stage 2: out[k][l] = (D @ sT^T)[k][l] * 1e-3
    k_s2g<<<dim3(NWG8), dim3(512), 0, stream>>>(D, sT, out);
}

// Round 12
// 92.880 us; speedup vs baseline: 1.5300x; 1.1796x over previous
//
#include <hip/hip_runtime.h>
#include <hip/hip_bf16.h>
#include <stdint.h>

#define NPIX 512
#define NBC  96
#define NWG8 (NBC * 4)      // 384 blocks: 96 images x 2x2 tiles of 256^2

typedef __attribute__((ext_vector_type(8))) short bf16x8;
typedef __attribute__((ext_vector_type(4))) float f32x4;
typedef __attribute__((ext_vector_type(8))) unsigned short u16x8;

__device__ __forceinline__ unsigned short f2bf(float f) {
    __hip_bfloat16 h = __float2bfloat16(f);
    union { __hip_bfloat16 h; unsigned short u; } v;
    v.h = h;
    return v.u;
}

#define GLD16(g, l) __builtin_amdgcn_global_load_lds( \
    (const __attribute__((address_space(1))) void*)(const void*)(g), \
    (__attribute__((address_space(3))) void*)(void*)(l), 16, 0, 0)

#define SBAR() do { __builtin_amdgcn_sched_barrier(0); \
                    __builtin_amdgcn_s_barrier(); \
                    __builtin_amdgcn_sched_barrier(0); } while (0)
#define LGKM0() do { asm volatile("s_waitcnt lgkmcnt(0)" ::: "memory"); \
                     __builtin_amdgcn_sched_barrier(0); } while (0)
#define SB0() __builtin_amdgcn_sched_barrier(0)
#define VMW(n) do { asm volatile("s_waitcnt vmcnt(" #n ")" ::: "memory"); } while (0)

// ---------------- D basis: D[k][n] = bf16(2*cos(pi*(2n+1)*k/1024)) ----------------
__global__ void k_basis(unsigned short* __restrict__ D) {
    int idx = blockIdx.x * 256 + threadIdx.x;
    int k = idx >> 9, n = idx & 511;
    int m = ((2 * n + 1) * k) & 2047;
    float ang = (float)m * 3.06796157577128218e-03f;  // pi/1024
    D[idx] = f2bf(2.0f * cosf(ang));
}

// ------------- Stage 1 (fused, fp32-B-in-LDS): sT[l][h] = bf16( sum_n D[l][n]*X[h][n] ) -------------
// Operand-swapped 256^2 schedule, BK=32, 16 K-tiles x 4 phases.
// A = D bf16, 2 slots x 16KB (GLD16).  B = X fp32, 3 slots x 32KB (GLD16, 7-phase lead).
// fp32->bf16 conversion at fragment-read time (VALU, hidden under MFMA).
// Per-iter issue FIFO: q0 A(T+1,h0)x1 | q1 B(T+2,h0)x2 | q2 B(T+2,h1)x2 | q3 A(T+1,h1)x1.
// Steady waits: q0 vmcnt(5), q2 vmcnt(3); q1/q3 none (already retired by q0's wait + barrier).
__global__ __launch_bounds__(512) void k_s1x(
        const unsigned short* __restrict__ D,
        const float* __restrict__ X,
        unsigned short* __restrict__ sT) {
    __shared__ __align__(16) char LDS[131072];   // A: 2x16KB @0 | B: 3x32KB @32768

    const int bid = blockIdx.x;
    const int nb  = (bid & 7) * (NWG8 / 8) + (bid >> 3);
    const int bc = nb >> 2, mt = (nb >> 1) & 1, nt = nb & 1;
    const int mA0 = mt * 256, nB0 = nt * 256;    // mA0: D rows (l), nB0: X rows (h)
    const unsigned short* Aimg = D;
    const float* Bimg = X + (size_t)bc * NPIX * NPIX;

    const int tid  = threadIdx.x;
    const int lane = tid & 63;
    const int wid  = tid >> 6;
    const int wr = wid >> 2, wc = wid & 3;       // 2x4 wave grid; wave C = 128x64
    const int rm = lane & 15;
    const int kq = lane >> 4;

    f32x4 acc[8][4] = {};
    bf16x8 a[4], b0[2], b1[2];

    // A half-tile: 128 rp-rows x 32 bf16 (64B), rows interleaved as before (H=mh).
    auto stageA = [&](int kt, int p2, int H) {
        int c = tid;                              // 512 chunks of 16B
        int rp = c >> 2, g = c & 3;
        int gs = g ^ (rp & 3);
        int row = ((rp >> 6) << 7) + H * 64 + (rp & 63);
        GLD16(Aimg + (size_t)(mA0 + row) * NPIX + kt * 32 + gs * 8,
              LDS + p2 * 16384 + H * 8192 + c * 16);
    };
    // B half-tile: 128 rp-rows x 32 fp32 (128B), rows interleaved as before (H=nh).
    auto stageB = [&](int kt, int s3, int H) {
        #pragma unroll
        for (int it = 0; it < 2; ++it) {
            int c = it * 512 + tid;               // 1024 chunks of 16B
            int rp = c >> 3, g = c & 7;
            int gs = g ^ (rp & 7);
            int row = ((rp >> 5) << 6) + H * 32 + (rp & 31);
            GLD16(Bimg + (size_t)(nB0 + row) * NPIX + kt * 32 + gs * 4,
                  LDS + 32768 + s3 * 32768 + H * 16384 + c * 16);
        }
    };
    auto readA = [&](int p2, int mh) {
        const char* base = LDS + p2 * 16384 + mh * 8192;
        #pragma unroll
        for (int f = 0; f < 4; ++f) {
            int rp = wr * 64 + f * 16 + rm;
            int slot = kq ^ (rm & 3);
            a[f] = *(const bf16x8*)(base + rp * 64 + slot * 16);
        }
    };
    auto readB = [&](int s3, int nh, bf16x8 (&b)[2]) {
        const char* base = LDS + 32768 + s3 * 32768 + nh * 16384;
        #pragma unroll
        for (int jj = 0; jj < 2; ++jj) {
            int rp = wc * 32 + jj * 16 + rm;
            const char* rb = base + rp * 128;
            f32x4 v0 = *(const f32x4*)(rb + (((kq * 2 + 0) ^ (rm & 7)) * 16));
            f32x4 v1 = *(const f32x4*)(rb + (((kq * 2 + 1) ^ (rm & 7)) * 16));
            bf16x8 t;
            t[0] = (short)f2bf(v0[0]); t[1] = (short)f2bf(v0[1]);
            t[2] = (short)f2bf(v0[2]); t[3] = (short)f2bf(v0[3]);
            t[4] = (short)f2bf(v1[0]); t[5] = (short)f2bf(v1[1]);
            t[6] = (short)f2bf(v1[2]); t[7] = (short)f2bf(v1[3]);
            b[jj] = t;
        }
    };
    auto mma = [&](int mh, int nh, bf16x8 (&b)[2]) {
        __builtin_amdgcn_s_setprio(1);
        #pragma unroll
        for (int f = 0; f < 4; ++f)
            #pragma unroll
            for (int jj = 0; jj < 2; ++jj)
                acc[mh * 4 + f][nh * 2 + jj] = __builtin_amdgcn_mfma_f32_16x16x32_bf16(
                    a[f], b[jj], acc[mh * 4 + f][nh * 2 + jj], 0, 0, 0);
        __builtin_amdgcn_s_setprio(0);
    };

    // --- prologue (mimics steady FIFO history): B0h0 B0h1 A0h0 B1h0 B1h1 A0h1 ---
    stageB(0, 0, 0); SB0();
    stageB(0, 0, 1); SB0();
    stageA(0, 0, 0); SB0();
    stageB(1, 1, 0); SB0();
    stageB(1, 1, 1); SB0();
    stageA(0, 0, 1); SB0();

    for (int T = 0; T < 14; ++T) {
        const int p2 = T & 1, p2n = p2 ^ 1;
        const int s3 = T % 3, s3b = (T + 2) % 3;
        // q0: retire A(T,h0) [+B(T,h0) older]; compute (0,0); issue A(T+1,h0)
        VMW(5); SBAR();
        readA(p2, 0); readB(s3, 0, b0);
        stageA(T + 1, p2n, 0); SB0();
        LGKM0(); mma(0, 0, b0);
        // q1: B(T,h1) already retired; compute (0,1); issue B(T+2,h0)
        SBAR();
        readB(s3, 1, b1);
        stageB(T + 2, s3b, 0); SB0();
        LGKM0(); mma(0, 1, b1);
        // q2: retire A(T,h1); compute (1,0); issue B(T+2,h1)
        VMW(3); SBAR();
        readA(p2, 1);
        stageB(T + 2, s3b, 1); SB0();
        LGKM0(); mma(1, 0, b0);
        // q3: compute (1,1); issue A(T+1,h1)
        SBAR();
        stageA(T + 1, p2n, 1); SB0();
        mma(1, 1, b1);
    }
    {   // T=14 (p2=0, s3=2): stage only A(15)
        VMW(5); SBAR();
        readA(0, 0); readB(2, 0, b0);
        stageA(15, 1, 0); SB0();
        LGKM0(); mma(0, 0, b0);
        SBAR();
        readB(2, 1, b1); LGKM0(); mma(0, 1, b1);
        VMW(1); SBAR();
        readA(0, 1); LGKM0(); mma(1, 0, b0);
        SBAR();
        stageA(15, 1, 1); SB0();
        mma(1, 1, b1);
    }
    {   // T=15 (p2=1, s3=0): no staging; drain 1 -> 0
        VMW(1); SBAR();
        readA(1, 0); readB(0, 0, b0); LGKM0(); mma(0, 0, b0);
        SBAR();
        readB(0, 1, b1); LGKM0(); mma(0, 1, b1);
        VMW(0); SBAR();
        readA(1, 1); LGKM0(); mma(1, 0, b0);
        SBAR();
        mma(1, 1, b1);
    }

    // Direct bf16 epilogue: C[l][h] row-major IS sT.
    unsigned short* Co = sT + (size_t)bc * NPIX * NPIX;
    #pragma unroll
    for (int mh = 0; mh < 2; ++mh)
        #pragma unroll
        for (int f = 0; f < 4; ++f) {
            int l_ = mA0 + wr * 128 + mh * 64 + f * 16 + kq * 4;
            #pragma unroll
            for (int nh = 0; nh < 2; ++nh)
                #pragma unroll
                for (int jj = 0; jj < 2; ++jj) {
                    int h_ = nB0 + wc * 64 + (nh * 2 + jj) * 16 + rm;
                    f32x4 v = acc[mh * 4 + f][nh * 2 + jj];
                    #pragma unroll
                    for (int r = 0; r < 4; ++r)
                        Co[(size_t)(l_ + r) * NPIX + h_] = f2bf(v[r]);
                }
        }
}

// ------------- Stage 2: out[k][l] = (D @ sT^T)[k][l] * 1e-3 (proven, byte-identical) -------------
__global__ __launch_bounds__(512) void k_s2g(
        const unsigned short* __restrict__ D,
        const unsigned short* __restrict__ sT,
        float* __restrict__ Cv) {
    __shared__ __align__(16) char LDS[131072];

    const int bid = blockIdx.x;
    const int nb  = (bid & 7) * (NWG8 / 8) + (bid >> 3);
    const int bc = nb >> 2, mt = (nb >> 1) & 1, nt = nb & 1;
    const int mA0 = mt * 256, nB0 = nt * 256;
    const unsigned short* Aimg = D;
    const unsigned short* Bimg = sT + (size_t)bc * NPIX * NPIX;

    const int tid  = threadIdx.x;
    const int lane = tid & 63;
    const int wid  = tid >> 6;
    const int wr = wid >> 2, wc = wid & 3;
    const int rm = lane & 15;
    const int kq = lane >> 4;

    f32x4 acc[8][4] = {};
    bf16x8 a[4][2], b0[2][2], b1[2][2];

    auto stageA = [&](int kt, int p, int H) {
        char* dst = LDS + p * 32768 + H * 16384;
        #pragma unroll
        for (int it = 0; it < 2; ++it) {
            int c = it * 512 + tid;
            int rp = c >> 3, g = c & 7;
            int gs = g ^ (rp & 7);
            int row = ((rp >> 6) << 7) + H * 64 + (rp & 63);
            GLD16(Aimg + (size_t)(mA0 + row) * NPIX + kt * 64 + gs * 8, dst + c * 16);
        }
    };
    auto stageB = [&](int kt, int p, int H) {
        char* dst = LDS + 65536 + p * 32768 + H * 16384;
        #pragma unroll
        for (int it = 0; it < 2; ++it) {
            int c = it * 512 + tid;
            int rp = c >> 3, g = c & 7;
            int gs = g ^ (rp & 7);
            int row = ((rp >> 5) << 6) + H * 32 + (rp & 31);
            GLD16(Bimg + (size_t)(nB0 + row) * NPIX + kt * 64 + gs * 8, dst + c * 16);
        }
    };
    auto readA = [&](int p, int mh) {
        const char* base = LDS + p * 32768 + mh * 16384;
        #pragma unroll
        for (int f = 0; f < 4; ++f) {
            int rp = wr * 64 + f * 16 + rm;
            #pragma unroll
            for (int ks = 0; ks < 2; ++ks) {
                int slot = (ks * 4 + kq) ^ (rm & 7);
                a[f][ks] = *(const bf16x8*)(base + rp * 128 + slot * 16);
            }
        }
    };
    auto readB = [&](int p, int nh, bf16x8 (&b)[2][2]) {
        const char* base = LDS + 65536 + p * 32768 + nh * 16384;
        #pragma unroll
        for (int jj = 0; jj < 2; ++jj) {
            int rp = wc * 32 + jj * 16 + rm;
            #pragma unroll
            for (int ks = 0; ks < 2; ++ks) {
                int slot = (ks * 4 + kq) ^ (rm & 7);
                b[jj][ks] = *(const bf16x8*)(base + rp * 128 + slot * 16);
            }
        }
    };
    auto mma = [&](int mh, int nh, bf16x8 (&b)[2][2]) {
        __builtin_amdgcn_s_setprio(1);
        #pragma unroll
        for (int f = 0; f < 4; ++f)
            #pragma unroll
            for (int jj = 0; jj < 2; ++jj)
                #pragma unroll
                for (int ks = 0; ks < 2; ++ks)
                    acc[mh * 4 + f][nh * 2 + jj] = __builtin_amdgcn_mfma_f32_16x16x32_bf16(
                        a[f][ks], b[jj][ks], acc[mh * 4 + f][nh * 2 + jj], 0, 0, 0);
        __builtin_amdgcn_s_setprio(0);
    };

    stageA(0, 0, 0); stageB(0, 0, 0); stageB(0, 0, 1); stageA(0, 0, 1);

    for (int T = 0; T < 7; ++T) {
        const int p = T & 1, pn = p ^ 1;
        asm volatile("s_waitcnt vmcnt(4)" ::: "memory"); SBAR();
        readA(p, 0); readB(p, 0, b0); stageA(T + 1, pn, 0);
        LGKM0(); mma(0, 0, b0);
        asm volatile("s_waitcnt vmcnt(4)" ::: "memory"); SBAR();
        readB(p, 1, b1); stageB(T + 1, pn, 0);
        LGKM0(); mma(0, 1, b1);
        asm volatile("s_waitcnt vmcnt(4)" ::: "memory"); SBAR();
        readA(p, 1); stageB(T + 1, pn, 1);
        LGKM0(); mma(1, 0, b0);
        SBAR();
        stageA(T + 1, pn, 1);
        mma(1, 1, b1);
    }
    {
        asm volatile("s_waitcnt vmcnt(4)" ::: "memory"); SBAR();
        readA(1, 0); readB(1, 0, b0); LGKM0(); mma(0, 0, b0);
        asm volatile("s_waitcnt vmcnt(2)" ::: "memory"); SBAR();
        readB(1, 1, b1); LGKM0(); mma(0, 1, b1);
        asm volatile("s_waitcnt vmcnt(0)" ::: "memory"); SBAR();
        readA(1, 1); LGKM0(); mma(1, 0, b0);
        SBAR();
        mma(1, 1, b1);
    }

    float* Co = Cv + (size_t)bc * NPIX * NPIX;
    #pragma unroll
    for (int mh = 0; mh < 2; ++mh)
        #pragma unroll
        for (int f = 0; f < 4; ++f) {
            int k_ = mA0 + wr * 128 + mh * 64 + f * 16 + kq * 4;
            #pragma unroll
            for (int nh = 0; nh < 2; ++nh)
                #pragma unroll
                for (int jj = 0; jj < 2; ++jj) {
                    int l_ = nB0 + wc * 64 + (nh * 2 + jj) * 16 + rm;
                    f32x4 v = acc[mh * 4 + f][nh * 2 + jj];
                    #pragma unroll
                    for (int r = 0; r < 4; ++r)
                        Co[(size_t)(k_ + r) * NPIX + l_] = v[r] * 1.0e-3f;
                }
        }
}

extern "C" void kernel_launch(void* const* d_in, const int* in_sizes, int n_in,
                              void* d_out, int out_size, void* d_ws, size_t ws_size,
                              hipStream_t stream) {
    const float* img = (const float*)d_in[0];
    float* out = (float*)d_out;

    unsigned short* D  = (unsigned short*)d_ws;                       // 512 KB
    unsigned short* sT = (unsigned short*)((char*)d_ws + 512 * 1024); // 48 MB

    k_basis<<<dim3(512 * 512 / 256), dim3(256), 0, stream>>>(D);

    // Stage 1 (fused fp32->bf16 via LDS, 7-phase B lead): sT[l][h] = sum_n D[l][n]*X[h][n]
    k_s1x<<<dim3(NWG8), dim3(512), 0, stream>>>(D, img, sT);

    // Stage 2: out[k][l] = (D @ sT^T)[k][l] * 1e-3
    k_s2g<<<dim3(NWG8), dim3(512), 0, stream>>>(D, sT, out);
}

// Round 13
// 84.387 us; speedup vs baseline: 1.6840x; 1.1006x over previous
//
#include <hip/hip_runtime.h>
#include <hip/hip_bf16.h>
#include <stdint.h>

#define NPIX 512
#define NBC  96
#define NWG8 (NBC * 4)       // 384 blocks for s2g
#define NWG13 (NBC * 8)      // 768 blocks for s1x (2 mt x 4 nt per image)

typedef __attribute__((ext_vector_type(8))) short bf16x8;
typedef __attribute__((ext_vector_type(4))) float f32x4;
typedef __attribute__((ext_vector_type(8))) unsigned short u16x8;

__device__ __forceinline__ unsigned short f2bf(float f) {
    __hip_bfloat16 h = __float2bfloat16(f);
    union { __hip_bfloat16 h; unsigned short u; } v;
    v.h = h;
    return v.u;
}

#define GLD16(g, l) __builtin_amdgcn_global_load_lds( \
    (const __attribute__((address_space(1))) void*)(const void*)(g), \
    (__attribute__((address_space(3))) void*)(void*)(l), 16, 0, 0)

#define SBAR() do { __builtin_amdgcn_sched_barrier(0); \
                    __builtin_amdgcn_s_barrier(); \
                    __builtin_amdgcn_sched_barrier(0); } while (0)
#define LGKM0() do { asm volatile("s_waitcnt lgkmcnt(0)" ::: "memory"); \
                     __builtin_amdgcn_sched_barrier(0); } while (0)
#define SB0() __builtin_amdgcn_sched_barrier(0)
#define VMW(n) do { asm volatile("s_waitcnt vmcnt(" #n ")" ::: "memory"); } while (0)

// ---------------- D basis: D[k][n] = bf16(2*cos(pi*(2n+1)*k/1024)) ----------------
__global__ void k_basis(unsigned short* __restrict__ D) {
    int idx = blockIdx.x * 256 + threadIdx.x;
    int k = idx >> 9, n = idx & 511;
    int m = ((2 * n + 1) * k) & 2047;
    float ang = (float)m * 3.06796157577128218e-03f;  // pi/1024
    D[idx] = f2bf(2.0f * cosf(ang));
}

// ------------- Stage 1 v2: sT[l][h] = bf16( sum_n D[l][n]*X[h][n] ), fused fp32 staging -------------
// Tile 256(l) x 128(h), BK=32, 16 K-tiles x 2 phases = 32 phases; 8 waves (2Mx4N), wave C = 128x32.
// LDS 80KB (A bf16 2x16KB, B fp32 3x16KB) -> 2 blocks/CU. A-swizzle fixed for conflict-free b128.
// Ledger (per-thread FIFO; issue per phase = [A(T+1,h), B(T+2,h)]): steady waits vmcnt(3)/vmcnt(3);
// tail T=14: 3/2, T=15: 1/0. B lead 3-4 phases, A lead 2 (D is L2-hot).
__global__ __launch_bounds__(512, 4) void k_s1x(
        const unsigned short* __restrict__ D,
        const float* __restrict__ X,
        unsigned short* __restrict__ sT) {
    __shared__ __align__(16) char LDS[81920];   // A: 2x16KB @0 | B: 3x16KB @32768

    const int bid = blockIdx.x;
    const int nb  = (bid & 7) * (NWG13 / 8) + (bid >> 3);
    const int bc = nb >> 3, mt = (nb >> 2) & 1, nt = nb & 3;
    const int mA0 = mt * 256, nB0 = nt * 128;   // mA0: D rows (l), nB0: X rows (h)
    const unsigned short* Aimg = D;
    const float* Bimg = X + (size_t)bc * NPIX * NPIX;

    const int tid  = threadIdx.x;
    const int lane = tid & 63;
    const int wid  = tid >> 6;
    const int wr = wid >> 2, wc = wid & 3;      // 2x4 wave grid; wave C = 128x32
    const int rm = lane & 15;
    const int kq = lane >> 4;

    f32x4 acc[8][2] = {};
    bf16x8 a[4], b[2];

    // A half-tile: 128 storage-rows x 32 bf16 (64B = 4 granules); 512 chunks = 1/thread.
    // Swizzle gs = g ^ ((rp>>1)&3)  [conflict-free read: granule%8 covers all 8]
    auto stageA = [&](int kt, int p2, int H) {
        int c = tid;
        int rp = c >> 2, g = c & 3;
        int gs = g ^ ((rp >> 1) & 3);
        int row = ((rp >> 6) << 7) + H * 64 + (rp & 63);
        GLD16(Aimg + (size_t)(mA0 + row) * NPIX + kt * 32 + gs * 8,
              LDS + p2 * 16384 + H * 8192 + c * 16);
    };
    // B half-tile: 64 storage-rows x 32 fp32 (128B = 8 granules); 512 chunks = 1/thread.
    auto stageB = [&](int kt, int s3, int H) {
        int c = tid;
        int rp = c >> 3, g = c & 7;
        int gs = g ^ (rp & 7);
        int row = ((rp >> 5) << 6) + H * 32 + (rp & 31);
        GLD16(Bimg + (size_t)(nB0 + row) * NPIX + kt * 32 + gs * 4,
              LDS + 32768 + s3 * 16384 + H * 8192 + c * 16);
    };
    auto readA = [&](int p2, int mh) {
        const char* base = LDS + p2 * 16384 + mh * 8192;
        #pragma unroll
        for (int f = 0; f < 4; ++f) {
            int rp = wr * 64 + f * 16 + rm;
            int slot = kq ^ ((rm >> 1) & 3);
            a[f] = *(const bf16x8*)(base + rp * 64 + slot * 16);
        }
    };
    auto readB = [&](int s3) {
        const char* base = LDS + 32768 + s3 * 16384 + (wc & 1) * 8192;
        #pragma unroll
        for (int jj = 0; jj < 2; ++jj) {
            int rp = (wc >> 1) * 32 + jj * 16 + rm;
            const char* rb = base + rp * 128;
            f32x4 v0 = *(const f32x4*)(rb + (((kq * 2 + 0) ^ (rm & 7)) * 16));
            f32x4 v1 = *(const f32x4*)(rb + (((kq * 2 + 1) ^ (rm & 7)) * 16));
            bf16x8 t;
            t[0] = (short)f2bf(v0[0]); t[1] = (short)f2bf(v0[1]);
            t[2] = (short)f2bf(v0[2]); t[3] = (short)f2bf(v0[3]);
            t[4] = (short)f2bf(v1[0]); t[5] = (short)f2bf(v1[1]);
            t[6] = (short)f2bf(v1[2]); t[7] = (short)f2bf(v1[3]);
            b[jj] = t;
        }
    };
    auto mma = [&](int mh) {
        __builtin_amdgcn_s_setprio(1);
        #pragma unroll
        for (int f = 0; f < 4; ++f)
            #pragma unroll
            for (int jj = 0; jj < 2; ++jj)
                acc[mh * 4 + f][jj] = __builtin_amdgcn_mfma_f32_16x16x32_bf16(
                    a[f], b[jj], acc[mh * 4 + f][jj], 0, 0, 0);
        __builtin_amdgcn_s_setprio(0);
    };

    // --- prologue (FIFO: B00 B01 A00 A01 B10 B11) ---
    stageB(0, 0, 0); SB0();
    stageB(0, 0, 1); SB0();
    stageA(0, 0, 0); SB0();
    stageA(0, 0, 1); SB0();
    stageB(1, 1, 0); SB0();
    stageB(1, 1, 1); SB0();

    for (int T = 0; T < 14; ++T) {
        const int p2 = T & 1, p2n = p2 ^ 1;
        const int s3 = T % 3, s3b = (T + 2) % 3;
        // ph0: needs A(T,h0)+B(T,both); issue A(T+1,0), B(T+2,0)
        VMW(3); SBAR();
        readA(p2, 0); readB(s3);
        stageA(T + 1, p2n, 0); SB0();
        stageB(T + 2, s3b, 0); SB0();
        LGKM0(); mma(0);
        // ph1: needs A(T,h1); issue A(T+1,1), B(T+2,1)
        VMW(3); SBAR();
        readA(p2, 1);
        stageA(T + 1, p2n, 1); SB0();
        stageB(T + 2, s3b, 1); SB0();
        LGKM0(); mma(1);
    }
    {   // T=14 (p2=0, s3=2): stage only A(15)
        VMW(3); SBAR();
        readA(0, 0); readB(2);
        stageA(15, 1, 0); SB0();
        LGKM0(); mma(0);
        VMW(2); SBAR();
        readA(0, 1);
        stageA(15, 1, 1); SB0();
        LGKM0(); mma(1);
    }
    {   // T=15 (p2=1, s3=0): drain 1 -> 0
        VMW(1); SBAR();
        readA(1, 0); readB(0);
        LGKM0(); mma(0);
        VMW(0); SBAR();
        readA(1, 1);
        LGKM0(); mma(1);
    }

    // Direct bf16 epilogue: C[l][h] row-major IS sT.
    unsigned short* Co = sT + (size_t)bc * NPIX * NPIX;
    #pragma unroll
    for (int mh = 0; mh < 2; ++mh)
        #pragma unroll
        for (int f = 0; f < 4; ++f) {
            int l_ = mA0 + wr * 128 + mh * 64 + f * 16 + kq * 4;
            #pragma unroll
            for (int jj = 0; jj < 2; ++jj) {
                int h_ = nB0 + wc * 32 + jj * 16 + rm;
                f32x4 v = acc[mh * 4 + f][jj];
                #pragma unroll
                for (int r = 0; r < 4; ++r)
                    Co[(size_t)(l_ + r) * NPIX + h_] = f2bf(v[r]);
            }
        }
}

// ------------- Stage 2: out[k][l] = (D @ sT^T)[k][l] * 1e-3 (proven roofline, unchanged) -------------
__global__ __launch_bounds__(512) void k_s2g(
        const unsigned short* __restrict__ D,
        const unsigned short* __restrict__ sT,
        float* __restrict__ Cv) {
    __shared__ __align__(16) char LDS[131072];

    const int bid = blockIdx.x;
    const int nb  = (bid & 7) * (NWG8 / 8) + (bid >> 3);
    const int bc = nb >> 2, mt = (nb >> 1) & 1, nt = nb & 1;
    const int mA0 = mt * 256, nB0 = nt * 256;
    const unsigned short* Aimg = D;
    const unsigned short* Bimg = sT + (size_t)bc * NPIX * NPIX;

    const int tid  = threadIdx.x;
    const int lane = tid & 63;
    const int wid  = tid >> 6;
    const int wr = wid >> 2, wc = wid & 3;
    const int rm = lane & 15;
    const int kq = lane >> 4;

    f32x4 acc[8][4] = {};
    bf16x8 a[4][2], b0[2][2], b1[2][2];

    auto stageA = [&](int kt, int p, int H) {
        char* dst = LDS + p * 32768 + H * 16384;
        #pragma unroll
        for (int it = 0; it < 2; ++it) {
            int c = it * 512 + tid;
            int rp = c >> 3, g = c & 7;
            int gs = g ^ (rp & 7);
            int row = ((rp >> 6) << 7) + H * 64 + (rp & 63);
            GLD16(Aimg + (size_t)(mA0 + row) * NPIX + kt * 64 + gs * 8, dst + c * 16);
        }
    };
    auto stageB = [&](int kt, int p, int H) {
        char* dst = LDS + 65536 + p * 32768 + H * 16384;
        #pragma unroll
        for (int it = 0; it < 2; ++it) {
            int c = it * 512 + tid;
            int rp = c >> 3, g = c & 7;
            int gs = g ^ (rp & 7);
            int row = ((rp >> 5) << 6) + H * 32 + (rp & 31);
            GLD16(Bimg + (size_t)(nB0 + row) * NPIX + kt * 64 + gs * 8, dst + c * 16);
        }
    };
    auto readA = [&](int p, int mh) {
        const char* base = LDS + p * 32768 + mh * 16384;
        #pragma unroll
        for (int f = 0; f < 4; ++f) {
            int rp = wr * 64 + f * 16 + rm;
            #pragma unroll
            for (int ks = 0; ks < 2; ++ks) {
                int slot = (ks * 4 + kq) ^ (rm & 7);
                a[f][ks] = *(const bf16x8*)(base + rp * 128 + slot * 16);
            }
        }
    };
    auto readB = [&](int p, int nh, bf16x8 (&b)[2][2]) {
        const char* base = LDS + 65536 + p * 32768 + nh * 16384;
        #pragma unroll
        for (int jj = 0; jj < 2; ++jj) {
            int rp = wc * 32 + jj * 16 + rm;
            #pragma unroll
            for (int ks = 0; ks < 2; ++ks) {
                int slot = (ks * 4 + kq) ^ (rm & 7);
                b[jj][ks] = *(const bf16x8*)(base + rp * 128 + slot * 16);
            }
        }
    };
    auto mma = [&](int mh, int nh, bf16x8 (&b)[2][2]) {
        __builtin_amdgcn_s_setprio(1);
        #pragma unroll
        for (int f = 0; f < 4; ++f)
            #pragma unroll
            for (int jj = 0; jj < 2; ++jj)
                #pragma unroll
                for (int ks = 0; ks < 2; ++ks)
                    acc[mh * 4 + f][nh * 2 + jj] = __builtin_amdgcn_mfma_f32_16x16x32_bf16(
                        a[f][ks], b[jj][ks], acc[mh * 4 + f][nh * 2 + jj], 0, 0, 0);
        __builtin_amdgcn_s_setprio(0);
    };

    stageA(0, 0, 0); stageB(0, 0, 0); stageB(0, 0, 1); stageA(0, 0, 1);

    for (int T = 0; T < 7; ++T) {
        const int p = T & 1, pn = p ^ 1;
        asm volatile("s_waitcnt vmcnt(4)" ::: "memory"); SBAR();
        readA(p, 0); readB(p, 0, b0); stageA(T + 1, pn, 0);
        LGKM0(); mma(0, 0, b0);
        asm volatile("s_waitcnt vmcnt(4)" ::: "memory"); SBAR();
        readB(p, 1, b1); stageB(T + 1, pn, 0);
        LGKM0(); mma(0, 1, b1);
        asm volatile("s_waitcnt vmcnt(4)" ::: "memory"); SBAR();
        readA(p, 1); stageB(T + 1, pn, 1);
        LGKM0(); mma(1, 0, b0);
        SBAR();
        stageA(T + 1, pn, 1);
        mma(1, 1, b1);
    }
    {
        asm volatile("s_waitcnt vmcnt(4)" ::: "memory"); SBAR();
        readA(1, 0); readB(1, 0, b0); LGKM0(); mma(0, 0, b0);
        asm volatile("s_waitcnt vmcnt(2)" ::: "memory"); SBAR();
        readB(1, 1, b1); LGKM0(); mma(0, 1, b1);
        asm volatile("s_waitcnt vmcnt(0)" ::: "memory"); SBAR();
        readA(1, 1); LGKM0(); mma(1, 0, b0);
        SBAR();
        mma(1, 1, b1);
    }

    float* Co = Cv + (size_t)bc * NPIX * NPIX;
    #pragma unroll
    for (int mh = 0; mh < 2; ++mh)
        #pragma unroll
        for (int f = 0; f < 4; ++f) {
            int k_ = mA0 + wr * 128 + mh * 64 + f * 16 + kq * 4;
            #pragma unroll
            for (int nh = 0; nh < 2; ++nh)
                #pragma unroll
                for (int jj = 0; jj < 2; ++jj) {
                    int l_ = nB0 + wc * 64 + (nh * 2 + jj) * 16 + rm;
                    f32x4 v = acc[mh * 4 + f][nh * 2 + jj];
                    #pragma unroll
                    for (int r = 0; r < 4; ++r)
                        Co[(size_t)(k_ + r) * NPIX + l_] = v[r] * 1.0e-3f;
                }
        }
}

extern "C" void kernel_launch(void* const* d_in, const int* in_sizes, int n_in,
                              void* d_out, int out_size, void* d_ws, size_t ws_size,
                              hipStream_t stream) {
    const float* img = (const float*)d_in[0];
    float* out = (float*)d_out;

    unsigned short* D  = (unsigned short*)d_ws;                       // 512 KB
    unsigned short* sT = (unsigned short*)((char*)d_ws + 512 * 1024); // 48 MB

    k_basis<<<dim3(512 * 512 / 256), dim3(256), 0, stream>>>(D);

    // Stage 1 v2 (fused fp32 staging, 2 blocks/CU, conflict-free): sT[l][h]
    k_s1x<<<dim3(NWG13), dim3(512), 0, stream>>>(D, img, sT);

    // Stage 2: out[k][l] = (D @ sT^T)[k][l] * 1e-3
    k_s2g<<<dim3(NWG8), dim3(512), 0, stream>>>(D, sT, out);
}

// Round 14
// 84.102 us; speedup vs baseline: 1.6897x; 1.0034x over previous
//
#include <hip/hip_runtime.h>
#include <hip/hip_bf16.h>
#include <stdint.h>

#define NPIX 512
#define NBC  96
#define NWG8 (NBC * 4)       // 384 blocks for s2g
#define NWG13 (NBC * 8)      // 768 blocks for s1x (2 mt x 4 nt per image)

typedef __attribute__((ext_vector_type(8))) short bf16x8;
typedef __attribute__((ext_vector_type(4))) float f32x4;
typedef __attribute__((ext_vector_type(8))) unsigned short u16x8;

__device__ __forceinline__ unsigned short f2bf(float f) {
    __hip_bfloat16 h = __float2bfloat16(f);
    union { __hip_bfloat16 h; unsigned short u; } v;
    v.h = h;
    return v.u;
}

#define GLD16(g, l) __builtin_amdgcn_global_load_lds( \
    (const __attribute__((address_space(1))) void*)(const void*)(g), \
    (__attribute__((address_space(3))) void*)(void*)(l), 16, 0, 0)

#define SBAR() do { __builtin_amdgcn_sched_barrier(0); \
                    __builtin_amdgcn_s_barrier(); \
                    __builtin_amdgcn_sched_barrier(0); } while (0)
#define LGKM0() do { asm volatile("s_waitcnt lgkmcnt(0)" ::: "memory"); \
                     __builtin_amdgcn_sched_barrier(0); } while (0)
#define SB0() __builtin_amdgcn_sched_barrier(0)
#define VMW(n) do { asm volatile("s_waitcnt vmcnt(" #n ")" ::: "memory"); } while (0)

// ---------------- D basis: D[k][n] = bf16(2*cos(pi*(2n+1)*k/1024)) ----------------
__global__ void k_basis(unsigned short* __restrict__ D) {
    int idx = blockIdx.x * 256 + threadIdx.x;
    int k = idx >> 9, n = idx & 511;
    int m = ((2 * n + 1) * k) & 2047;
    float ang = (float)m * 3.06796157577128218e-03f;  // pi/1024
    D[idx] = f2bf(2.0f * cosf(ang));
}

// ------------- Stage 1 v3: sT[l][h] = bf16( sum_n D[l][n]*X[h][n] ), fused fp32 staging -------------
// Tile 256(l) x 128(h), BK=32, 16 K-tiles = 16 PHASES (one barrier each), 16 MFMA/phase.
// 8 waves (2Mx4N), wave C = 128x32. LDS 80KB (A bf16 2x16KB, B fp32 3x16KB) -> 2 blocks/CU.
// FIFO ledger: phase T issues [A(T+1)x2, B(T+2)x2] right after the barrier.
// Entering T: outstanding [B(T)(done), A(T)2, B(T+1)2] -> steady wait vmcnt(2).
// Tail: T=14 issues A(15) only; T=15 waits vmcnt(0).
__global__ __launch_bounds__(512, 4) void k_s1x(
        const unsigned short* __restrict__ D,
        const float* __restrict__ X,
        unsigned short* __restrict__ sT) {
    __shared__ __align__(16) char LDS[81920];   // A: 2x16KB @0 | B: 3x16KB @32768

    const int bid = blockIdx.x;
    const int nb  = (bid & 7) * (NWG13 / 8) + (bid >> 3);
    const int bc = nb >> 3, mt = (nb >> 2) & 1, nt = nb & 3;
    const int mA0 = mt * 256, nB0 = nt * 128;   // mA0: D rows (l), nB0: X rows (h)
    const unsigned short* Aimg = D;
    const float* Bimg = X + (size_t)bc * NPIX * NPIX;

    const int tid  = threadIdx.x;
    const int lane = tid & 63;
    const int wid  = tid >> 6;
    const int wr = wid >> 2, wc = wid & 3;      // 2x4 wave grid; wave C = 128x32
    const int rm = lane & 15;
    const int kq = lane >> 4;

    f32x4 acc[8][2] = {};
    bf16x8 a[4], b[2];

    // A FULL tile: 256 storage-rows x 32 bf16 (64B); 1024 chunks -> 2 GLD16/thread.
    auto stageA = [&](int kt, int p2) {
        #pragma unroll
        for (int it = 0; it < 2; ++it) {
            int c = it * 512 + tid;
            int rp = c >> 2, g = c & 3;
            int gs = g ^ ((rp >> 1) & 3);
            int row = ((rp >> 7) << 7) + ((rp >> 6) & 1) * 64 + (rp & 63);  // = rp
            GLD16(Aimg + (size_t)(mA0 + row) * NPIX + kt * 32 + gs * 8,
                  LDS + p2 * 16384 + c * 16);
        }
    };
    // B FULL tile: 128 storage-rows x 32 fp32 (128B); 1024 chunks -> 2 GLD16/thread.
    auto stageB = [&](int kt, int s3) {
        #pragma unroll
        for (int it = 0; it < 2; ++it) {
            int c = it * 512 + tid;
            int rp = c >> 3, g = c & 7;
            int gs = g ^ (rp & 7);
            GLD16(Bimg + (size_t)(nB0 + rp) * NPIX + kt * 32 + gs * 4,
                  LDS + 32768 + s3 * 16384 + c * 16);
        }
    };
    auto readA = [&](int p2, int mh) {
        const char* base = LDS + p2 * 16384 + mh * 8192;
        #pragma unroll
        for (int f = 0; f < 4; ++f) {
            int rp = mh * 128 + wr * 64 + f * 16 + rm;   // storage row (local within tile half)
            int slot = kq ^ ((rp >> 1) & 3);
            a[f] = *(const bf16x8*)(LDS + p2 * 16384 + rp * 64 + slot * 16);
        }
        (void)base;
    };
    auto readB = [&](int s3) {
        #pragma unroll
        for (int jj = 0; jj < 2; ++jj) {
            int rp = wc * 32 + jj * 16 + rm;
            const char* rb = LDS + 32768 + s3 * 16384 + rp * 128;
            f32x4 v0 = *(const f32x4*)(rb + (((kq * 2 + 0) ^ (rp & 7)) * 16));
            f32x4 v1 = *(const f32x4*)(rb + (((kq * 2 + 1) ^ (rp & 7)) * 16));
            bf16x8 t;
            t[0] = (short)f2bf(v0[0]); t[1] = (short)f2bf(v0[1]);
            t[2] = (short)f2bf(v0[2]); t[3] = (short)f2bf(v0[3]);
            t[4] = (short)f2bf(v1[0]); t[5] = (short)f2bf(v1[1]);
            t[6] = (short)f2bf(v1[2]); t[7] = (short)f2bf(v1[3]);
            b[jj] = t;
        }
    };
    auto mma = [&](int mh) {
        __builtin_amdgcn_s_setprio(1);
        #pragma unroll
        for (int f = 0; f < 4; ++f)
            #pragma unroll
            for (int jj = 0; jj < 2; ++jj)
                acc[mh * 4 + f][jj] = __builtin_amdgcn_mfma_f32_16x16x32_bf16(
                    a[f], b[jj], acc[mh * 4 + f][jj], 0, 0, 0);
        __builtin_amdgcn_s_setprio(0);
    };

    // --- prologue (FIFO: B0, A0, B1 -> entering T=0 outstanding matches steady) ---
    stageB(0, 0); SB0();
    stageA(0, 0); SB0();
    stageB(1, 1); SB0();

    for (int T = 0; T < 16; ++T) {
        const int p2 = T & 1, p2n = p2 ^ 1;
        const int s3 = T % 3, s3b = (T + 2) % 3;
        if (T < 15) { VMW(2); } else { VMW(0); }
        SBAR();
        if (T + 1 < 16) { stageA(T + 1, p2n); SB0(); }
        if (T + 2 < 16) { stageB(T + 2, s3b); SB0(); }
        readB(s3);
        readA(p2, 0);
        LGKM0(); mma(0);
        readA(p2, 1);
        LGKM0(); mma(1);
    }

    // Direct bf16 epilogue: C[l][h] row-major IS sT.
    unsigned short* Co = sT + (size_t)bc * NPIX * NPIX;
    #pragma unroll
    for (int mh = 0; mh < 2; ++mh)
        #pragma unroll
        for (int f = 0; f < 4; ++f) {
            int l_ = mA0 + mh * 128 + wr * 64 + f * 16 + kq * 4;
            #pragma unroll
            for (int jj = 0; jj < 2; ++jj) {
                int h_ = nB0 + wc * 32 + jj * 16 + rm;
                f32x4 v = acc[mh * 4 + f][jj];
                #pragma unroll
                for (int r = 0; r < 4; ++r)
                    Co[(size_t)(l_ + r) * NPIX + h_] = f2bf(v[r]);
            }
        }
}

// ------------- Stage 2: out[k][l] = (D @ sT^T)[k][l] * 1e-3 (proven roofline, unchanged) -------------
__global__ __launch_bounds__(512) void k_s2g(
        const unsigned short* __restrict__ D,
        const unsigned short* __restrict__ sT,
        float* __restrict__ Cv) {
    __shared__ __align__(16) char LDS[131072];

    const int bid = blockIdx.x;
    const int nb  = (bid & 7) * (NWG8 / 8) + (bid >> 3);
    const int bc = nb >> 2, mt = (nb >> 1) & 1, nt = nb & 1;
    const int mA0 = mt * 256, nB0 = nt * 256;
    const unsigned short* Aimg = D;
    const unsigned short* Bimg = sT + (size_t)bc * NPIX * NPIX;

    const int tid  = threadIdx.x;
    const int lane = tid & 63;
    const int wid  = tid >> 6;
    const int wr = wid >> 2, wc = wid & 3;
    const int rm = lane & 15;
    const int kq = lane >> 4;

    f32x4 acc[8][4] = {};
    bf16x8 a[4][2], b0[2][2], b1[2][2];

    auto stageA = [&](int kt, int p, int H) {
        char* dst = LDS + p * 32768 + H * 16384;
        #pragma unroll
        for (int it = 0; it < 2; ++it) {
            int c = it * 512 + tid;
            int rp = c >> 3, g = c & 7;
            int gs = g ^ (rp & 7);
            int row = ((rp >> 6) << 7) + H * 64 + (rp & 63);
            GLD16(Aimg + (size_t)(mA0 + row) * NPIX + kt * 64 + gs * 8, dst + c * 16);
        }
    };
    auto stageB = [&](int kt, int p, int H) {
        char* dst = LDS + 65536 + p * 32768 + H * 16384;
        #pragma unroll
        for (int it = 0; it < 2; ++it) {
            int c = it * 512 + tid;
            int rp = c >> 3, g = c & 7;
            int gs = g ^ (rp & 7);
            int row = ((rp >> 5) << 6) + H * 32 + (rp & 31);
            GLD16(Bimg + (size_t)(nB0 + row) * NPIX + kt * 64 + gs * 8, dst + c * 16);
        }
    };
    auto readA = [&](int p, int mh) {
        const char* base = LDS + p * 32768 + mh * 16384;
        #pragma unroll
        for (int f = 0; f < 4; ++f) {
            int rp = wr * 64 + f * 16 + rm;
            #pragma unroll
            for (int ks = 0; ks < 2; ++ks) {
                int slot = (ks * 4 + kq) ^ (rm & 7);
                a[f][ks] = *(const bf16x8*)(base + rp * 128 + slot * 16);
            }
        }
    };
    auto readB = [&](int p, int nh, bf16x8 (&b)[2][2]) {
        const char* base = LDS + 65536 + p * 32768 + nh * 16384;
        #pragma unroll
        for (int jj = 0; jj < 2; ++jj) {
            int rp = wc * 32 + jj * 16 + rm;
            #pragma unroll
            for (int ks = 0; ks < 2; ++ks) {
                int slot = (ks * 4 + kq) ^ (rm & 7);
                b[jj][ks] = *(const bf16x8*)(base + rp * 128 + slot * 16);
            }
        }
    };
    auto mma = [&](int mh, int nh, bf16x8 (&b)[2][2]) {
        __builtin_amdgcn_s_setprio(1);
        #pragma unroll
        for (int f = 0; f < 4; ++f)
            #pragma unroll
            for (int jj = 0; jj < 2; ++jj)
                #pragma unroll
                for (int ks = 0; ks < 2; ++ks)
                    acc[mh * 4 + f][nh * 2 + jj] = __builtin_amdgcn_mfma_f32_16x16x32_bf16(
                        a[f][ks], b[jj][ks], acc[mh * 4 + f][nh * 2 + jj], 0, 0, 0);
        __builtin_amdgcn_s_setprio(0);
    };

    stageA(0, 0, 0); stageB(0, 0, 0); stageB(0, 0, 1); stageA(0, 0, 1);

    for (int T = 0; T < 7; ++T) {
        const int p = T & 1, pn = p ^ 1;
        asm volatile("s_waitcnt vmcnt(4)" ::: "memory"); SBAR();
        readA(p, 0); readB(p, 0, b0); stageA(T + 1, pn, 0);
        LGKM0(); mma(0, 0, b0);
        asm volatile("s_waitcnt vmcnt(4)" ::: "memory"); SBAR();
        readB(p, 1, b1); stageB(T + 1, pn, 0);
        LGKM0(); mma(0, 1, b1);
        asm volatile("s_waitcnt vmcnt(4)" ::: "memory"); SBAR();
        readA(p, 1); stageB(T + 1, pn, 1);
        LGKM0(); mma(1, 0, b0);
        SBAR();
        stageA(T + 1, pn, 1);
        mma(1, 1, b1);
    }
    {
        asm volatile("s_waitcnt vmcnt(4)" ::: "memory"); SBAR();
        readA(1, 0); readB(1, 0, b0); LGKM0(); mma(0, 0, b0);
        asm volatile("s_waitcnt vmcnt(2)" ::: "memory"); SBAR();
        readB(1, 1, b1); LGKM0(); mma(0, 1, b1);
        asm volatile("s_waitcnt vmcnt(0)" ::: "memory"); SBAR();
        readA(1, 1); LGKM0(); mma(1, 0, b0);
        SBAR();
        mma(1, 1, b1);
    }

    float* Co = Cv + (size_t)bc * NPIX * NPIX;
    #pragma unroll
    for (int mh = 0; mh < 2; ++mh)
        #pragma unroll
        for (int f = 0; f < 4; ++f) {
            int k_ = mA0 + wr * 128 + mh * 64 + f * 16 + kq * 4;
            #pragma unroll
            for (int nh = 0; nh < 2; ++nh)
                #pragma unroll
                for (int jj = 0; jj < 2; ++jj) {
                    int l_ = nB0 + wc * 64 + (nh * 2 + jj) * 16 + rm;
                    f32x4 v = acc[mh * 4 + f][nh * 2 + jj];
                    #pragma unroll
                    for (int r = 0; r < 4; ++r)
                        Co[(size_t)(k_ + r) * NPIX + l_] = v[r] * 1.0e-3f;
                }
        }
}

extern "C" void kernel_launch(void* const* d_in, const int* in_sizes, int n_in,
                              void* d_out, int out_size, void* d_ws, size_t ws_size,
                              hipStream_t stream) {
    const float* img = (const float*)d_in[0];
    float* out = (float*)d_out;

    unsigned short* D  = (unsigned short*)d_ws;                       // 512 KB
    unsigned short* sT = (unsigned short*)((char*)d_ws + 512 * 1024); // 48 MB

    k_basis<<<dim3(512 * 512 / 256), dim3(256), 0, stream>>>(D);

    // Stage 1 v3 (16 single-barrier phases, fused fp32 staging): sT[l][h]
    k_s1x<<<dim3(NWG13), dim3(512), 0, stream>>>(D, img, sT);

    // Stage 2: out[k][l] = (D @ sT^T)[k][l] * 1e-3
    k_s2g<<<dim3(NWG8), dim3(512), 0, stream>>>(D, sT, out);
}